// Round 3
// baseline (7549.792 us; speedup 1.0000x reference)
//
#include <hip/hip_runtime.h>
#include <hip/hip_bf16.h>

typedef unsigned int u32;

#define NPTS 120000
#define N1PTS 15000
#define NCLSS 17

static inline int cdiv(int a, int b) { return (a + b - 1) / b; }

// ---------------- split sparse conv (gather-GEMM) + fused bn stats ----------------
// S = CSPLIT*KSPLIT threads cooperate on one point.
//   sub_c selects a CIN/CSPLIT channel chunk, sub_k a k-subset (stride KSPLIT).
// Partial acc[COUT] per thread -> group butterfly (all S lanes end with full acc)
// -> lane sub==0 stores; stats completed by coset butterfly over remaining lane bits.
template<int K, int CIN, int COUT, int CSPLIT, int KSPLIT, bool IDENT>
__global__ __launch_bounds__(256) void conv_split(
    const float* __restrict__ src, const int* __restrict__ nbr,
    const float* __restrict__ W, float* __restrict__ out,
    float* __restrict__ stats, int M)
{
    constexpr int S = CSPLIT * KSPLIT;
    constexpr int CC = CIN / CSPLIT;          // channels handled per lane
    static_assert(COUT == 32, "stats layout assumes COUT==32");
    static_assert((S & (S - 1)) == 0 && S <= 64, "S must be pow2 <= 64");

    int g = blockIdx.x * 256 + threadIdx.x;
    int p = g / S;
    int sub = g & (S - 1);
    int sub_c = sub & (CSPLIT - 1);
    int sub_k = sub / CSPLIT;

    float acc[COUT];
#pragma unroll
    for (int o = 0; o < COUT; ++o) acc[o] = 0.f;

    if (p < M) {
#pragma unroll 1
        for (int k = sub_k; k < K; k += KSPLIT) {
            int idx = IDENT ? p : nbr[(size_t)p * K + k];
            if (idx >= 0) {
                const float* __restrict__ xr = src + (size_t)idx * CIN + sub_c * CC;
                const float* __restrict__ wk = W + ((size_t)k * CIN + sub_c * CC) * COUT;
                if constexpr ((CC % 4) == 0) {
                    float xv[CC];
#pragma unroll
                    for (int c = 0; c < CC; c += 4) {
                        float4 v = *reinterpret_cast<const float4*>(xr + c);
                        xv[c] = v.x; xv[c + 1] = v.y; xv[c + 2] = v.z; xv[c + 3] = v.w;
                    }
#pragma unroll
                    for (int c = 0; c < CC; ++c)
#pragma unroll
                        for (int o = 0; o < COUT; ++o)
                            acc[o] = fmaf(xv[c], wk[c * COUT + o], acc[o]);
                } else {
                    float xv[CC];
#pragma unroll
                    for (int c = 0; c < CC; ++c) xv[c] = xr[c];
#pragma unroll
                    for (int c = 0; c < CC; ++c)
#pragma unroll
                        for (int o = 0; o < COUT; ++o)
                            acc[o] = fmaf(xv[c], wk[c * COUT + o], acc[o]);
                }
            }
        }
    }

    // group butterfly: after this every lane of the S-group holds the full acc
#pragma unroll
    for (int m = 1; m < S; m <<= 1)
#pragma unroll
        for (int o = 0; o < COUT; ++o)
            acc[o] += __shfl_xor(acc[o], m, 64);

    // store (group leader only; static register indexing)
    if (p < M && sub == 0) {
#pragma unroll
        for (int o = 0; o < COUT; o += 4) {
            float4 v; v.x = acc[o]; v.y = acc[o + 1]; v.z = acc[o + 2]; v.w = acc[o + 3];
            *reinterpret_cast<float4*>(out + (size_t)p * COUT + o) = v;
        }
    }

    // stats: coset butterfly over remaining lane bits (one lane per group per coset
    // -> each point counted exactly once for both sum and sum-of-squares)
    int lane = threadIdx.x & 63;
    int wid = threadIdx.x >> 6;
    float sel1 = 0.f, sel2 = 0.f;
#pragma unroll
    for (int o = 0; o < COUT; ++o) {
        float s1 = acc[o];
        float s2 = acc[o] * acc[o];
#pragma unroll
        for (int m = S; m <= 32; m <<= 1) { s1 += __shfl_xor(s1, m, 64); s2 += __shfl_xor(s2, m, 64); }
        if (lane == o) sel1 = s1;
        if (lane == o + 32) sel2 = s2;
    }
    float val = (lane < 32) ? sel1 : sel2;
    __shared__ float red[4][64];
    red[wid][lane] = val;
    __syncthreads();
    if (wid == 0) {
        float t = red[0][lane] + red[1][lane] + red[2][lane] + red[3][lane];
        atomicAdd(&stats[lane], t);
    }
}

// ---------------- bn (training-mode batch stats) apply, in place ----------------
template<bool RELU>
__global__ __launch_bounds__(256) void bn_apply(
    float* __restrict__ buf, const float* __restrict__ stats,
    const float* __restrict__ gb, float invM, int total4)
{
    int i = blockIdx.x * 256 + threadIdx.x;
    if (i >= total4) return;
    int c0 = (i & 7) * 4;
    float4 v = reinterpret_cast<float4*>(buf)[i];
    float r[4] = { v.x, v.y, v.z, v.w };
#pragma unroll
    for (int j = 0; j < 4; ++j) {
        int c = c0 + j;
        float mu = stats[c] * invM;
        float var = fmaxf(stats[32 + c] * invM - mu * mu, 0.f);
        float a = gb[c] * rsqrtf(var + 1e-5f);
        float b = gb[32 + c] - mu * a;
        float y = fmaf(a, r[j], b);
        if (RELU) y = fmaxf(y, 0.f);
        r[j] = y;
    }
    v.x = r[0]; v.y = r[1]; v.z = r[2]; v.w = r[3];
    reinterpret_cast<float4*>(buf)[i] = v;
}

// bn+relu on u (raw) into cat[:,0:32], copy x0 into cat[:,32:64]
__global__ __launch_bounds__(256) void bnrelu_cat(
    const float* __restrict__ u, const float* __restrict__ x0,
    float* __restrict__ cat, const float* __restrict__ stats,
    const float* __restrict__ gb, float invM, int total8)
{
    int i = blockIdx.x * 256 + threadIdx.x;
    if (i >= total8) return;
    int p = i >> 3, j = i & 7;
    int c0 = j * 4;
    float4 v = *reinterpret_cast<const float4*>(u + (size_t)p * 32 + c0);
    float r[4] = { v.x, v.y, v.z, v.w };
#pragma unroll
    for (int t = 0; t < 4; ++t) {
        int c = c0 + t;
        float mu = stats[c] * invM;
        float var = fmaxf(stats[32 + c] * invM - mu * mu, 0.f);
        float a = gb[c] * rsqrtf(var + 1e-5f);
        float b = gb[32 + c] - mu * a;
        r[t] = fmaxf(fmaf(a, r[t], b), 0.f);
    }
    v.x = r[0]; v.y = r[1]; v.z = r[2]; v.w = r[3];
    *reinterpret_cast<float4*>(cat + (size_t)p * 64 + c0) = v;
    float4 w = *reinterpret_cast<const float4*>(x0 + (size_t)p * 32 + c0);
    *reinterpret_cast<float4*>(cat + (size_t)p * 64 + 32 + c0) = w;
}

// ---------------- attention ----------------
// att layout (floats): [0]=max (uint-encoded), [1]=S, [2..33]=z, [34..65]=ctx
__global__ __launch_bounds__(256) void att_logits(
    const float* __restrict__ net, const float* __restrict__ wi,
    const float* __restrict__ bi, float* __restrict__ lbuf,
    u32* __restrict__ mx, int M)
{
    int p = blockIdx.x * 256 + threadIdx.x;
    float l = -3.0e38f;
    if (p < M) {
        float s = bi[0];
#pragma unroll
        for (int c = 0; c < 32; c += 4) {
            float4 v = *reinterpret_cast<const float4*>(net + (size_t)p * 32 + c);
            s = fmaf(v.x, wi[c], s); s = fmaf(v.y, wi[c + 1], s);
            s = fmaf(v.z, wi[c + 2], s); s = fmaf(v.w, wi[c + 3], s);
        }
        lbuf[p] = s;
        l = s;
    }
#pragma unroll
    for (int m = 1; m <= 32; m <<= 1) l = fmaxf(l, __shfl_xor(l, m, 64));
    if ((threadIdx.x & 63) == 0) {
        u32 b = __float_as_uint(l);
        u32 e = (b & 0x80000000u) ? ~b : (b | 0x80000000u);
        atomicMax(mx, e);
    }
}

__global__ __launch_bounds__(256) void att_accum(
    const float* __restrict__ net, const float* __restrict__ lbuf,
    float* __restrict__ att, int M)
{
    int p = blockIdx.x * 256 + threadIdx.x;
    int lane = threadIdx.x & 63, wid = threadIdx.x >> 6;
    u32 um = __float_as_uint(att[0]);
    float mx = (um & 0x80000000u) ? __uint_as_float(um ^ 0x80000000u) : __uint_as_float(~um);
    float w = 0.f;
    float nv[32];
#pragma unroll
    for (int c = 0; c < 32; ++c) nv[c] = 0.f;
    if (p < M) {
        w = expf(lbuf[p] - mx);
#pragma unroll
        for (int c = 0; c < 32; c += 4) {
            float4 v = *reinterpret_cast<const float4*>(net + (size_t)p * 32 + c);
            nv[c] = v.x; nv[c + 1] = v.y; nv[c + 2] = v.z; nv[c + 3] = v.w;
        }
    }
    float sel = 0.f;
#pragma unroll
    for (int c = 0; c < 32; ++c) {
        float s = w * nv[c];
#pragma unroll
        for (int m = 1; m <= 32; m <<= 1) s += __shfl_xor(s, m, 64);
        if (lane == c) sel = s;
    }
    {
        float s = w;
#pragma unroll
        for (int m = 1; m <= 32; m <<= 1) s += __shfl_xor(s, m, 64);
        if (lane == 32) sel = s;
    }
    __shared__ float red[4][33];
    if (lane < 33) red[wid][lane] = sel;
    __syncthreads();
    if (wid == 0 && lane < 33) {
        float t = red[0][lane] + red[1][lane] + red[2][lane] + red[3][lane];
        atomicAdd(lane < 32 ? &att[2 + lane] : &att[1], t);
    }
}

__global__ void att_ctx_k(const float* __restrict__ wk, const float* __restrict__ bk,
                          float* __restrict__ att)
{
    int o = threadIdx.x;
    if (o >= 32) return;
    float invS = 1.0f / att[1];
    float s = bk[o];
#pragma unroll
    for (int c = 0; c < 32; ++c) s = fmaf(att[2 + c] * invS, wk[c * 32 + o], s);
    att[34 + o] = s;
}

// v = (net@wv+bv)*ctx ; r = relu(v@wo + bo + d)
__global__ __launch_bounds__(256) void att_out_res(
    const float* __restrict__ net, const float* __restrict__ d,
    const float* __restrict__ wv, const float* __restrict__ bv,
    const float* __restrict__ wo, const float* __restrict__ bo,
    const float* __restrict__ att, float* __restrict__ r, int M)
{
    int p = blockIdx.x * 256 + threadIdx.x;
    if (p >= M) return;
    float nv[32];
#pragma unroll
    for (int c = 0; c < 32; c += 4) {
        float4 v = *reinterpret_cast<const float4*>(net + (size_t)p * 32 + c);
        nv[c] = v.x; nv[c + 1] = v.y; nv[c + 2] = v.z; nv[c + 3] = v.w;
    }
    float vv[32];
#pragma unroll
    for (int o = 0; o < 32; ++o) {
        float s = bv[o];
#pragma unroll
        for (int c = 0; c < 32; ++c) s = fmaf(nv[c], wv[c * 32 + o], s);
        vv[o] = s * att[34 + o];
    }
#pragma unroll
    for (int oo = 0; oo < 32; ++oo) {
        float s = bo[oo];
#pragma unroll
        for (int o = 0; o < 32; ++o) s = fmaf(vv[o], wo[o * 32 + oo], s);
        float rr = s + d[(size_t)p * 32 + oo];
        r[(size_t)p * 32 + oo] = fmaxf(rr, 0.f);
    }
}

// ---------------- final: y = relu(bn(net2) + bn(ds)); out = y@Wcls + bcls ----------------
__global__ __launch_bounds__(256) void final_cls(
    const float* __restrict__ net2, const float* __restrict__ dsr,
    const float* __restrict__ st7, const float* __restrict__ st8,
    const float* __restrict__ gb7, const float* __restrict__ gb8,
    const float* __restrict__ wcls, const float* __restrict__ bcls,
    float* __restrict__ outp, float invM, int M)
{
    int p = blockIdx.x * 256 + threadIdx.x;
    if (p >= M) return;
    float y[32];
#pragma unroll
    for (int c = 0; c < 32; ++c) {
        float mu1 = st7[c] * invM;
        float var1 = fmaxf(st7[32 + c] * invM - mu1 * mu1, 0.f);
        float a1 = gb7[c] * rsqrtf(var1 + 1e-5f);
        float b1 = gb7[32 + c] - mu1 * a1;
        float mu2 = st8[c] * invM;
        float var2 = fmaxf(st8[32 + c] * invM - mu2 * mu2, 0.f);
        float a2 = gb8[c] * rsqrtf(var2 + 1e-5f);
        float b2 = gb8[32 + c] - mu2 * a2;
        float t = fmaf(a1, net2[(size_t)p * 32 + c], b1) + fmaf(a2, dsr[(size_t)p * 32 + c], b2);
        y[c] = fmaxf(t, 0.f);
    }
#pragma unroll
    for (int j = 0; j < NCLSS; ++j) {
        float s = bcls[j];
#pragma unroll
        for (int c = 0; c < 32; ++c) s = fmaf(y[c], wcls[c * NCLSS + j], s);
        outp[(size_t)p * NCLSS + j] = s;
    }
}

// ---------------- host ----------------
extern "C" void kernel_launch(void* const* d_in, const int* in_sizes, int n_in,
                              void* d_out, int out_size, void* d_ws, size_t ws_size,
                              hipStream_t stream)
{
    float* ws = (float*)d_ws;

    // workspace layout (floats)
    const size_t OFF_ST = 0;                   // 9*64 stats + 66 att = 642
    const size_t OFF_A  = 704;                 // N*32
    const size_t OFF_B  = OFF_A + 3840000;     // N*32
    const size_t OFF_C  = OFF_B + 3840000;     // N1*32
    const size_t OFF_D  = OFF_C + 480000;      // N1*32
    const size_t OFF_E  = OFF_D + 480000;      // N1*32
    const size_t OFF_L  = OFF_E + 480000;      // N1 logits (pad 15040)
    const size_t OFF_F  = OFF_L + 15040;       // N*64 (cat); first N*32 reused as net2 (G)

    float* A = ws + OFF_A;
    float* B = ws + OFF_B;
    float* C = ws + OFF_C;
    float* D = ws + OFF_D;
    float* E = ws + OFF_E;
    float* L = ws + OFF_L;
    float* F = ws + OFF_F;
    float* G = F;                              // fuse2 output overwrites cat (dead by then)
    float* ST = ws + OFF_ST;
    float* ATT = ST + 576;

    // inputs (fp32 per reference dtypes)
    const float* X        = (const float*)d_in[0];
    const float* Wstem0   = (const float*)d_in[1];
    const float* gb_stem0 = (const float*)d_in[2];
    const float* Wstem1   = (const float*)d_in[3];
    const float* gb_stem1 = (const float*)d_in[4];
    const float* Wdown    = (const float*)d_in[5];
    const float* gb_down  = (const float*)d_in[6];
    const float* Wres1    = (const float*)d_in[7];
    const float* gb_res1  = (const float*)d_in[8];
    const float* Wres2    = (const float*)d_in[9];
    const float* gb_res2  = (const float*)d_in[10];
    const float* wi = (const float*)d_in[11];
    const float* bi = (const float*)d_in[12];
    const float* wk = (const float*)d_in[13];
    const float* bk = (const float*)d_in[14];
    const float* wv = (const float*)d_in[15];
    const float* bv = (const float*)d_in[16];
    const float* wo = (const float*)d_in[17];
    const float* bo = (const float*)d_in[18];
    const float* Wup      = (const float*)d_in[19];
    const float* gb_up    = (const float*)d_in[20];
    const float* Wfuse1   = (const float*)d_in[21];
    const float* gb_fuse1 = (const float*)d_in[22];
    const float* Wfuse2   = (const float*)d_in[23];
    const float* gb_fuse2 = (const float*)d_in[24];
    const float* Wds      = (const float*)d_in[25];
    const float* gb_ds    = (const float*)d_in[26];
    const float* Wcls     = (const float*)d_in[27];
    const float* bcls     = (const float*)d_in[28];

    const int* nbr0     = (const int*)d_in[29];
    const int* nbr_down = (const int*)d_in[30];
    const int* nbr1     = (const int*)d_in[31];
    const int* nbr_up   = (const int*)d_in[32];

    const float invN  = 1.0f / (float)NPTS;
    const float invN1 = 1.0f / (float)N1PTS;

    // zero stats + att accumulators
    hipMemsetAsync((void*)ST, 0, 642 * sizeof(float), stream);

    const int gBN = cdiv(NPTS * 32 / 4, 256);   // 3750
    const int gBN1 = cdiv(N1PTS * 32 / 4, 256); // 469
    const int gN = cdiv(NPTS, 256);

    // stem: stem0 k-split x4 (CIN=3), stem1 c-split x4
    hipLaunchKernelGGL((conv_split<27, 3, 32, 1, 4, false>), dim3(cdiv(NPTS * 4, 256)), dim3(256), 0, stream,
                       X, nbr0, Wstem0, A, ST + 0 * 64, NPTS);
    hipLaunchKernelGGL((bn_apply<true>), dim3(gBN), dim3(256), 0, stream,
                       A, ST + 0 * 64, gb_stem0, invN, NPTS * 8);
    hipLaunchKernelGGL((conv_split<27, 32, 32, 4, 1, false>), dim3(cdiv(NPTS * 4, 256)), dim3(256), 0, stream,
                       A, nbr0, Wstem1, B, ST + 1 * 64, NPTS);
    hipLaunchKernelGGL((bn_apply<true>), dim3(gBN), dim3(256), 0, stream,
                       B, ST + 1 * 64, gb_stem1, invN, NPTS * 8);   // B = x0

    // downsample: c-split x4, k-split x2
    hipLaunchKernelGGL((conv_split<8, 32, 32, 4, 2, false>), dim3(cdiv(N1PTS * 8, 256)), dim3(256), 0, stream,
                       B, nbr_down, Wdown, C, ST + 2 * 64, N1PTS);
    hipLaunchKernelGGL((bn_apply<true>), dim3(gBN1), dim3(256), 0, stream,
                       C, ST + 2 * 64, gb_down, invN1, N1PTS * 8);  // C = d

    // residual block convs: c-split x4, k-split x4 (N1 is small)
    hipLaunchKernelGGL((conv_split<27, 32, 32, 4, 4, false>), dim3(cdiv(N1PTS * 16, 256)), dim3(256), 0, stream,
                       C, nbr1, Wres1, D, ST + 3 * 64, N1PTS);
    hipLaunchKernelGGL((bn_apply<true>), dim3(gBN1), dim3(256), 0, stream,
                       D, ST + 3 * 64, gb_res1, invN1, N1PTS * 8);
    hipLaunchKernelGGL((conv_split<27, 32, 32, 4, 4, false>), dim3(cdiv(N1PTS * 16, 256)), dim3(256), 0, stream,
                       D, nbr1, Wres2, E, ST + 4 * 64, N1PTS);
    hipLaunchKernelGGL((bn_apply<false>), dim3(gBN1), dim3(256), 0, stream,
                       E, ST + 4 * 64, gb_res2, invN1, N1PTS * 8);  // E = net

    // attention + residual add (writes r into D)
    hipLaunchKernelGGL(att_logits, dim3(cdiv(N1PTS, 256)), dim3(256), 0, stream,
                       E, wi, bi, L, (u32*)ATT, N1PTS);
    hipLaunchKernelGGL(att_accum, dim3(cdiv(N1PTS, 256)), dim3(256), 0, stream, E, L, ATT, N1PTS);
    hipLaunchKernelGGL(att_ctx_k, dim3(1), dim3(64), 0, stream, wk, bk, ATT);
    hipLaunchKernelGGL(att_out_res, dim3(cdiv(N1PTS, 256)), dim3(256), 0, stream,
                       E, C, wv, bv, wo, bo, ATT, D, N1PTS);        // D = r

    // upsample + cat: c-split x4, k-split x2
    hipLaunchKernelGGL((conv_split<8, 32, 32, 4, 2, false>), dim3(cdiv(NPTS * 8, 256)), dim3(256), 0, stream,
                       D, nbr_up, Wup, A, ST + 5 * 64, NPTS);
    hipLaunchKernelGGL(bnrelu_cat, dim3(gBN), dim3(256), 0, stream,
                       A, B, F, ST + 5 * 64, gb_up, invN, NPTS * 8); // F = cat

    // fuse residual block: ds first (frees F for reuse), then fuse1/fuse2
    hipLaunchKernelGGL((conv_split<1, 64, 32, 4, 1, true>), dim3(cdiv(NPTS * 4, 256)), dim3(256), 0, stream,
                       F, (const int*)nullptr, Wds, B, ST + 8 * 64, NPTS); // B = ds raw
    hipLaunchKernelGGL((conv_split<27, 64, 32, 4, 1, false>), dim3(cdiv(NPTS * 4, 256)), dim3(256), 0, stream,
                       F, nbr0, Wfuse1, A, ST + 6 * 64, NPTS);
    hipLaunchKernelGGL((bn_apply<true>), dim3(gBN), dim3(256), 0, stream,
                       A, ST + 6 * 64, gb_fuse1, invN, NPTS * 8);
    hipLaunchKernelGGL((conv_split<27, 32, 32, 4, 1, false>), dim3(cdiv(NPTS * 4, 256)), dim3(256), 0, stream,
                       A, nbr0, Wfuse2, G, ST + 7 * 64, NPTS);       // G = net2 raw (overwrites cat)

    // final fuse + classifier
    hipLaunchKernelGGL(final_cls, dim3(gN), dim3(256), 0, stream,
                       G, B, ST + 7 * 64, ST + 8 * 64, gb_fuse2, gb_ds,
                       Wcls, bcls, (float*)d_out, invN, NPTS);
}

// Round 4
// 1155.612 us; speedup vs baseline: 6.5332x; 6.5332x over previous
//
#include <hip/hip_runtime.h>
#include <hip/hip_bf16.h>

typedef unsigned int u32;

#define NPTS 120000
#define N1PTS 15000
#define NCLSS 17

static inline int cdiv(int a, int b) { return (a + b - 1) / b; }

// ---------------- shared epilogue: cross-wave reduce + store + bn stats ----------------
// Block = 4 waves x 64 lanes; lane owns point p; each wave holds a k-partial acc[32].
// Two 16-channel rounds through padded LDS; wave 0 ends with the full sum,
// stores it, and does the stats butterfly (sum + sum-of-squares per channel).
__device__ __forceinline__ void reduce_store_stats(
    float (&acc)[32], int lane, int wid, bool act, int p,
    float* __restrict__ out, float* __restrict__ stats)
{
    __shared__ float lds[3][64][17];
#pragma unroll
    for (int r = 0; r < 2; ++r) {
        if (wid > 0) {
#pragma unroll
            for (int j = 0; j < 16; ++j) lds[wid - 1][lane][j] = acc[r * 16 + j];
        }
        __syncthreads();
        if (wid == 0) {
#pragma unroll
            for (int w = 0; w < 3; ++w)
#pragma unroll
                for (int j = 0; j < 16; ++j) acc[r * 16 + j] += lds[w][lane][j];
        }
        __syncthreads();
    }
    if (wid == 0) {
        if (act) {
#pragma unroll
            for (int o = 0; o < 32; o += 4) {
                float4 v; v.x = acc[o]; v.y = acc[o + 1]; v.z = acc[o + 2]; v.w = acc[o + 3];
                *reinterpret_cast<float4*>(out + (size_t)p * 32 + o) = v;
            }
        } else {
#pragma unroll
            for (int o = 0; o < 32; ++o) acc[o] = 0.f;
        }
        float sel1 = 0.f, sel2 = 0.f;
#pragma unroll
        for (int o = 0; o < 32; ++o) {
            float s1 = acc[o];
            float s2 = acc[o] * acc[o];
#pragma unroll
            for (int m = 1; m <= 32; m <<= 1) { s1 += __shfl_xor(s1, m, 64); s2 += __shfl_xor(s2, m, 64); }
            if (lane == o) sel1 = s1;
            if (lane == o + 32) sel2 = s2;
        }
        atomicAdd(&stats[lane], lane < 32 ? sel1 : sel2);
    }
}

// ---------------- sparse conv, k split across the 4 waves ----------------
// W address depends only on (k = wid + 4j, c, o): wave-uniform -> scalar loads.
template<int K, int CIN>
__global__ __launch_bounds__(256, 8) void conv_ksplit(
    const float* __restrict__ src, const int* __restrict__ nbr,
    const float* __restrict__ W, float* __restrict__ out,
    float* __restrict__ stats, int M)
{
    constexpr int COUT = 32;
    int lane = threadIdx.x & 63;
    int wid = __builtin_amdgcn_readfirstlane(threadIdx.x >> 6);
    int p = blockIdx.x * 64 + lane;
    bool act = p < M;

    float acc[COUT];
#pragma unroll
    for (int o = 0; o < COUT; ++o) acc[o] = 0.f;

#pragma unroll 1
    for (int k = wid; k < K; k += 4) {
        int idx = act ? nbr[(size_t)p * K + k] : -1;
        if (idx >= 0) {
            const float* __restrict__ xr = src + (size_t)idx * CIN;
            const float* __restrict__ wk = W + (size_t)k * CIN * COUT;
            if constexpr ((CIN % 8) == 0) {
#pragma unroll
                for (int c0 = 0; c0 < CIN; c0 += 8) {
                    float4 v0 = *reinterpret_cast<const float4*>(xr + c0);
                    float4 v1 = *reinterpret_cast<const float4*>(xr + c0 + 4);
                    float xv[8] = { v0.x, v0.y, v0.z, v0.w, v1.x, v1.y, v1.z, v1.w };
#pragma unroll
                    for (int c = 0; c < 8; ++c)
#pragma unroll
                        for (int o = 0; o < COUT; ++o)
                            acc[o] = fmaf(xv[c], wk[(c0 + c) * COUT + o], acc[o]);
                }
            } else {
                float xv[CIN];
#pragma unroll
                for (int c = 0; c < CIN; ++c) xv[c] = xr[c];
#pragma unroll
                for (int c = 0; c < CIN; ++c)
#pragma unroll
                    for (int o = 0; o < COUT; ++o)
                        acc[o] = fmaf(xv[c], wk[c * COUT + o], acc[o]);
            }
        }
    }
    reduce_store_stats(acc, lane, wid, act, p, out, stats);
}

// ---------------- 1x1 identity conv (ds shortcut), channels split across waves ----------------
__global__ __launch_bounds__(256, 8) void conv_ds64(
    const float* __restrict__ src, const float* __restrict__ W,
    float* __restrict__ out, float* __restrict__ stats, int M)
{
    int lane = threadIdx.x & 63;
    int wid = __builtin_amdgcn_readfirstlane(threadIdx.x >> 6);
    int p = blockIdx.x * 64 + lane;
    bool act = p < M;

    float acc[32];
#pragma unroll
    for (int o = 0; o < 32; ++o) acc[o] = 0.f;

    if (act) {
        const float* __restrict__ xr = src + (size_t)p * 64 + wid * 16;
        const float* __restrict__ wk = W + wid * 16 * 32;   // wave-uniform
#pragma unroll
        for (int c0 = 0; c0 < 16; c0 += 8) {
            float4 v0 = *reinterpret_cast<const float4*>(xr + c0);
            float4 v1 = *reinterpret_cast<const float4*>(xr + c0 + 4);
            float xv[8] = { v0.x, v0.y, v0.z, v0.w, v1.x, v1.y, v1.z, v1.w };
#pragma unroll
            for (int c = 0; c < 8; ++c)
#pragma unroll
                for (int o = 0; o < 32; ++o)
                    acc[o] = fmaf(xv[c], wk[(c0 + c) * 32 + o], acc[o]);
        }
    }
    reduce_store_stats(acc, lane, wid, act, p, out, stats);
}

// ---------------- bn (training-mode batch stats) apply, in place ----------------
template<bool RELU>
__global__ __launch_bounds__(256) void bn_apply(
    float* __restrict__ buf, const float* __restrict__ stats,
    const float* __restrict__ gb, float invM, int total4)
{
    int i = blockIdx.x * 256 + threadIdx.x;
    if (i >= total4) return;
    int c0 = (i & 7) * 4;
    float4 v = reinterpret_cast<float4*>(buf)[i];
    float r[4] = { v.x, v.y, v.z, v.w };
#pragma unroll
    for (int j = 0; j < 4; ++j) {
        int c = c0 + j;
        float mu = stats[c] * invM;
        float var = fmaxf(stats[32 + c] * invM - mu * mu, 0.f);
        float a = gb[c] * rsqrtf(var + 1e-5f);
        float b = gb[32 + c] - mu * a;
        float y = fmaf(a, r[j], b);
        if (RELU) y = fmaxf(y, 0.f);
        r[j] = y;
    }
    v.x = r[0]; v.y = r[1]; v.z = r[2]; v.w = r[3];
    reinterpret_cast<float4*>(buf)[i] = v;
}

// bn+relu on u (raw) into cat[:,0:32], copy x0 into cat[:,32:64]
__global__ __launch_bounds__(256) void bnrelu_cat(
    const float* __restrict__ u, const float* __restrict__ x0,
    float* __restrict__ cat, const float* __restrict__ stats,
    const float* __restrict__ gb, float invM, int total8)
{
    int i = blockIdx.x * 256 + threadIdx.x;
    if (i >= total8) return;
    int p = i >> 3, j = i & 7;
    int c0 = j * 4;
    float4 v = *reinterpret_cast<const float4*>(u + (size_t)p * 32 + c0);
    float r[4] = { v.x, v.y, v.z, v.w };
#pragma unroll
    for (int t = 0; t < 4; ++t) {
        int c = c0 + t;
        float mu = stats[c] * invM;
        float var = fmaxf(stats[32 + c] * invM - mu * mu, 0.f);
        float a = gb[c] * rsqrtf(var + 1e-5f);
        float b = gb[32 + c] - mu * a;
        r[t] = fmaxf(fmaf(a, r[t], b), 0.f);
    }
    v.x = r[0]; v.y = r[1]; v.z = r[2]; v.w = r[3];
    *reinterpret_cast<float4*>(cat + (size_t)p * 64 + c0) = v;
    float4 w = *reinterpret_cast<const float4*>(x0 + (size_t)p * 32 + c0);
    *reinterpret_cast<float4*>(cat + (size_t)p * 64 + 32 + c0) = w;
}

// ---------------- attention ----------------
// att layout (floats): [0]=max (uint-encoded), [1]=S, [2..33]=z, [34..65]=ctx
__global__ __launch_bounds__(256) void att_logits(
    const float* __restrict__ net, const float* __restrict__ wi,
    const float* __restrict__ bi, float* __restrict__ lbuf,
    u32* __restrict__ mx, int M)
{
    int p = blockIdx.x * 256 + threadIdx.x;
    float l = -3.0e38f;
    if (p < M) {
        float s = bi[0];
#pragma unroll
        for (int c = 0; c < 32; c += 4) {
            float4 v = *reinterpret_cast<const float4*>(net + (size_t)p * 32 + c);
            s = fmaf(v.x, wi[c], s); s = fmaf(v.y, wi[c + 1], s);
            s = fmaf(v.z, wi[c + 2], s); s = fmaf(v.w, wi[c + 3], s);
        }
        lbuf[p] = s;
        l = s;
    }
#pragma unroll
    for (int m = 1; m <= 32; m <<= 1) l = fmaxf(l, __shfl_xor(l, m, 64));
    if ((threadIdx.x & 63) == 0) {
        u32 b = __float_as_uint(l);
        u32 e = (b & 0x80000000u) ? ~b : (b | 0x80000000u);
        atomicMax(mx, e);
    }
}

__global__ __launch_bounds__(256) void att_accum(
    const float* __restrict__ net, const float* __restrict__ lbuf,
    float* __restrict__ att, int M)
{
    int p = blockIdx.x * 256 + threadIdx.x;
    int lane = threadIdx.x & 63, wid = threadIdx.x >> 6;
    u32 um = __float_as_uint(att[0]);
    float mx = (um & 0x80000000u) ? __uint_as_float(um ^ 0x80000000u) : __uint_as_float(~um);
    float w = 0.f;
    float nv[32];
#pragma unroll
    for (int c = 0; c < 32; ++c) nv[c] = 0.f;
    if (p < M) {
        w = expf(lbuf[p] - mx);
#pragma unroll
        for (int c = 0; c < 32; c += 4) {
            float4 v = *reinterpret_cast<const float4*>(net + (size_t)p * 32 + c);
            nv[c] = v.x; nv[c + 1] = v.y; nv[c + 2] = v.z; nv[c + 3] = v.w;
        }
    }
    float sel = 0.f;
#pragma unroll
    for (int c = 0; c < 32; ++c) {
        float s = w * nv[c];
#pragma unroll
        for (int m = 1; m <= 32; m <<= 1) s += __shfl_xor(s, m, 64);
        if (lane == c) sel = s;
    }
    {
        float s = w;
#pragma unroll
        for (int m = 1; m <= 32; m <<= 1) s += __shfl_xor(s, m, 64);
        if (lane == 32) sel = s;
    }
    __shared__ float red[4][33];
    if (lane < 33) red[wid][lane] = sel;
    __syncthreads();
    if (wid == 0 && lane < 33) {
        float t = red[0][lane] + red[1][lane] + red[2][lane] + red[3][lane];
        atomicAdd(lane < 32 ? &att[2 + lane] : &att[1], t);
    }
}

__global__ void att_ctx_k(const float* __restrict__ wk, const float* __restrict__ bk,
                          float* __restrict__ att)
{
    int o = threadIdx.x;
    if (o >= 32) return;
    float invS = 1.0f / att[1];
    float s = bk[o];
#pragma unroll
    for (int c = 0; c < 32; ++c) s = fmaf(att[2 + c] * invS, wk[c * 32 + o], s);
    att[34 + o] = s;
}

// v = (net@wv+bv)*ctx ; r = relu(v@wo + bo + d)
__global__ __launch_bounds__(256) void att_out_res(
    const float* __restrict__ net, const float* __restrict__ d,
    const float* __restrict__ wv, const float* __restrict__ bv,
    const float* __restrict__ wo, const float* __restrict__ bo,
    const float* __restrict__ att, float* __restrict__ r, int M)
{
    int p = blockIdx.x * 256 + threadIdx.x;
    if (p >= M) return;
    float nv[32];
#pragma unroll
    for (int c = 0; c < 32; c += 4) {
        float4 v = *reinterpret_cast<const float4*>(net + (size_t)p * 32 + c);
        nv[c] = v.x; nv[c + 1] = v.y; nv[c + 2] = v.z; nv[c + 3] = v.w;
    }
    float vv[32];
#pragma unroll
    for (int o = 0; o < 32; ++o) {
        float s = bv[o];
#pragma unroll
        for (int c = 0; c < 32; ++c) s = fmaf(nv[c], wv[c * 32 + o], s);
        vv[o] = s * att[34 + o];
    }
#pragma unroll
    for (int oo = 0; oo < 32; ++oo) {
        float s = bo[oo];
#pragma unroll
        for (int o = 0; o < 32; ++o) s = fmaf(vv[o], wo[o * 32 + oo], s);
        float rr = s + d[(size_t)p * 32 + oo];
        r[(size_t)p * 32 + oo] = fmaxf(rr, 0.f);
    }
}

// ---------------- final: y = relu(bn(net2) + bn(ds)); out = y@Wcls + bcls ----------------
__global__ __launch_bounds__(256) void final_cls(
    const float* __restrict__ net2, const float* __restrict__ dsr,
    const float* __restrict__ st7, const float* __restrict__ st8,
    const float* __restrict__ gb7, const float* __restrict__ gb8,
    const float* __restrict__ wcls, const float* __restrict__ bcls,
    float* __restrict__ outp, float invM, int M)
{
    int p = blockIdx.x * 256 + threadIdx.x;
    if (p >= M) return;
    float y[32];
#pragma unroll
    for (int c = 0; c < 32; ++c) {
        float mu1 = st7[c] * invM;
        float var1 = fmaxf(st7[32 + c] * invM - mu1 * mu1, 0.f);
        float a1 = gb7[c] * rsqrtf(var1 + 1e-5f);
        float b1 = gb7[32 + c] - mu1 * a1;
        float mu2 = st8[c] * invM;
        float var2 = fmaxf(st8[32 + c] * invM - mu2 * mu2, 0.f);
        float a2 = gb8[c] * rsqrtf(var2 + 1e-5f);
        float b2 = gb8[32 + c] - mu2 * a2;
        float t = fmaf(a1, net2[(size_t)p * 32 + c], b1) + fmaf(a2, dsr[(size_t)p * 32 + c], b2);
        y[c] = fmaxf(t, 0.f);
    }
#pragma unroll
    for (int j = 0; j < NCLSS; ++j) {
        float s = bcls[j];
#pragma unroll
        for (int c = 0; c < 32; ++c) s = fmaf(y[c], wcls[c * NCLSS + j], s);
        outp[(size_t)p * NCLSS + j] = s;
    }
}

// ---------------- host ----------------
extern "C" void kernel_launch(void* const* d_in, const int* in_sizes, int n_in,
                              void* d_out, int out_size, void* d_ws, size_t ws_size,
                              hipStream_t stream)
{
    float* ws = (float*)d_ws;

    // workspace layout (floats)
    const size_t OFF_ST = 0;                   // 9*64 stats + 66 att = 642
    const size_t OFF_A  = 704;                 // N*32
    const size_t OFF_B  = OFF_A + 3840000;     // N*32
    const size_t OFF_C  = OFF_B + 3840000;     // N1*32
    const size_t OFF_D  = OFF_C + 480000;      // N1*32
    const size_t OFF_E  = OFF_D + 480000;      // N1*32
    const size_t OFF_L  = OFF_E + 480000;      // N1 logits (pad 15040)
    const size_t OFF_F  = OFF_L + 15040;       // N*64 (cat); first N*32 reused as net2 (G)

    float* A = ws + OFF_A;
    float* B = ws + OFF_B;
    float* C = ws + OFF_C;
    float* D = ws + OFF_D;
    float* E = ws + OFF_E;
    float* L = ws + OFF_L;
    float* F = ws + OFF_F;
    float* G = F;                              // fuse2 output overwrites cat (dead by then)
    float* ST = ws + OFF_ST;
    float* ATT = ST + 576;

    // inputs (fp32 per reference dtypes)
    const float* X        = (const float*)d_in[0];
    const float* Wstem0   = (const float*)d_in[1];
    const float* gb_stem0 = (const float*)d_in[2];
    const float* Wstem1   = (const float*)d_in[3];
    const float* gb_stem1 = (const float*)d_in[4];
    const float* Wdown    = (const float*)d_in[5];
    const float* gb_down  = (const float*)d_in[6];
    const float* Wres1    = (const float*)d_in[7];
    const float* gb_res1  = (const float*)d_in[8];
    const float* Wres2    = (const float*)d_in[9];
    const float* gb_res2  = (const float*)d_in[10];
    const float* wi = (const float*)d_in[11];
    const float* bi = (const float*)d_in[12];
    const float* wk = (const float*)d_in[13];
    const float* bk = (const float*)d_in[14];
    const float* wv = (const float*)d_in[15];
    const float* bv = (const float*)d_in[16];
    const float* wo = (const float*)d_in[17];
    const float* bo = (const float*)d_in[18];
    const float* Wup      = (const float*)d_in[19];
    const float* gb_up    = (const float*)d_in[20];
    const float* Wfuse1   = (const float*)d_in[21];
    const float* gb_fuse1 = (const float*)d_in[22];
    const float* Wfuse2   = (const float*)d_in[23];
    const float* gb_fuse2 = (const float*)d_in[24];
    const float* Wds      = (const float*)d_in[25];
    const float* gb_ds    = (const float*)d_in[26];
    const float* Wcls     = (const float*)d_in[27];
    const float* bcls     = (const float*)d_in[28];

    const int* nbr0     = (const int*)d_in[29];
    const int* nbr_down = (const int*)d_in[30];
    const int* nbr1     = (const int*)d_in[31];
    const int* nbr_up   = (const int*)d_in[32];

    const float invN  = 1.0f / (float)NPTS;
    const float invN1 = 1.0f / (float)N1PTS;

    // zero stats + att accumulators
    hipMemsetAsync((void*)ST, 0, 642 * sizeof(float), stream);

    const int gKN  = cdiv(NPTS, 64);            // 1875 blocks (4 waves each)
    const int gKN1 = cdiv(N1PTS, 64);           // 235
    const int gBN  = cdiv(NPTS * 32 / 4, 256);  // 3750
    const int gBN1 = cdiv(N1PTS * 32 / 4, 256); // 469
    const int gN   = cdiv(NPTS, 256);

    // stem
    hipLaunchKernelGGL((conv_ksplit<27, 3>), dim3(gKN), dim3(256), 0, stream,
                       X, nbr0, Wstem0, A, ST + 0 * 64, NPTS);
    hipLaunchKernelGGL((bn_apply<true>), dim3(gBN), dim3(256), 0, stream,
                       A, ST + 0 * 64, gb_stem0, invN, NPTS * 8);
    hipLaunchKernelGGL((conv_ksplit<27, 32>), dim3(gKN), dim3(256), 0, stream,
                       A, nbr0, Wstem1, B, ST + 1 * 64, NPTS);
    hipLaunchKernelGGL((bn_apply<true>), dim3(gBN), dim3(256), 0, stream,
                       B, ST + 1 * 64, gb_stem1, invN, NPTS * 8);   // B = x0

    // downsample
    hipLaunchKernelGGL((conv_ksplit<8, 32>), dim3(gKN1), dim3(256), 0, stream,
                       B, nbr_down, Wdown, C, ST + 2 * 64, N1PTS);
    hipLaunchKernelGGL((bn_apply<true>), dim3(gBN1), dim3(256), 0, stream,
                       C, ST + 2 * 64, gb_down, invN1, N1PTS * 8);  // C = d

    // residual block convs
    hipLaunchKernelGGL((conv_ksplit<27, 32>), dim3(gKN1), dim3(256), 0, stream,
                       C, nbr1, Wres1, D, ST + 3 * 64, N1PTS);
    hipLaunchKernelGGL((bn_apply<true>), dim3(gBN1), dim3(256), 0, stream,
                       D, ST + 3 * 64, gb_res1, invN1, N1PTS * 8);
    hipLaunchKernelGGL((conv_ksplit<27, 32>), dim3(gKN1), dim3(256), 0, stream,
                       D, nbr1, Wres2, E, ST + 4 * 64, N1PTS);
    hipLaunchKernelGGL((bn_apply<false>), dim3(gBN1), dim3(256), 0, stream,
                       E, ST + 4 * 64, gb_res2, invN1, N1PTS * 8);  // E = net

    // attention + residual add (writes r into D)
    hipLaunchKernelGGL(att_logits, dim3(cdiv(N1PTS, 256)), dim3(256), 0, stream,
                       E, wi, bi, L, (u32*)ATT, N1PTS);
    hipLaunchKernelGGL(att_accum, dim3(cdiv(N1PTS, 256)), dim3(256), 0, stream, E, L, ATT, N1PTS);
    hipLaunchKernelGGL(att_ctx_k, dim3(1), dim3(64), 0, stream, wk, bk, ATT);
    hipLaunchKernelGGL(att_out_res, dim3(cdiv(N1PTS, 256)), dim3(256), 0, stream,
                       E, C, wv, bv, wo, bo, ATT, D, N1PTS);        // D = r

    // upsample + cat
    hipLaunchKernelGGL((conv_ksplit<8, 32>), dim3(gKN), dim3(256), 0, stream,
                       D, nbr_up, Wup, A, ST + 5 * 64, NPTS);
    hipLaunchKernelGGL(bnrelu_cat, dim3(gBN), dim3(256), 0, stream,
                       A, B, F, ST + 5 * 64, gb_up, invN, NPTS * 8); // F = cat

    // fuse residual block: ds first, then fuse1/fuse2
    hipLaunchKernelGGL(conv_ds64, dim3(gKN), dim3(256), 0, stream,
                       F, Wds, B, ST + 8 * 64, NPTS);                // B = ds raw
    hipLaunchKernelGGL((conv_ksplit<27, 64>), dim3(gKN), dim3(256), 0, stream,
                       F, nbr0, Wfuse1, A, ST + 6 * 64, NPTS);
    hipLaunchKernelGGL((bn_apply<true>), dim3(gBN), dim3(256), 0, stream,
                       A, ST + 6 * 64, gb_fuse1, invN, NPTS * 8);
    hipLaunchKernelGGL((conv_ksplit<27, 32>), dim3(gKN), dim3(256), 0, stream,
                       A, nbr0, Wfuse2, G, ST + 7 * 64, NPTS);       // G = net2 raw (overwrites cat)

    // final fuse + classifier
    hipLaunchKernelGGL(final_cls, dim3(gN), dim3(256), 0, stream,
                       G, B, ST + 7 * 64, ST + 8 * 64, gb_fuse2, gb_ds,
                       Wcls, bcls, (float*)d_out, invN, NPTS);
}

// Round 5
// 917.045 us; speedup vs baseline: 8.2327x; 1.2601x over previous
//
#include <hip/hip_runtime.h>

typedef unsigned int u32;
typedef unsigned short u16;

#define NPTS 120000
#define N1PTS 15000
#define NCLSS 17

static inline int cdiv(int a, int b) { return (a + b - 1) / b; }

// bf16 helpers (storage-only bf16; all math fp32)
__device__ __forceinline__ float bflo(u32 u) { return __uint_as_float(u << 16); }
__device__ __forceinline__ float bfhi(u32 u) { return __uint_as_float(u & 0xFFFF0000u); }
__device__ __forceinline__ u32 f2bf(float f) {   // RNE
    u32 u = __float_as_uint(f);
    return (u + 0x7FFFu + ((u >> 16) & 1u)) >> 16;
}
__device__ __forceinline__ u32 pack2(float a, float b) { return f2bf(a) | (f2bf(b) << 16); }

// ---------------- shared epilogue: cross-wave reduce + bf16 store + bn stats ----------------
__device__ __forceinline__ void reduce_store_stats(
    float (&acc)[32], int lane, int wid, bool act, int p,
    u16* __restrict__ out, float* __restrict__ stats)
{
    __shared__ float lds[3][64][17];
#pragma unroll
    for (int r = 0; r < 2; ++r) {
        if (wid > 0) {
#pragma unroll
            for (int j = 0; j < 16; ++j) lds[wid - 1][lane][j] = acc[r * 16 + j];
        }
        __syncthreads();
        if (wid == 0) {
#pragma unroll
            for (int w = 0; w < 3; ++w)
#pragma unroll
                for (int j = 0; j < 16; ++j) acc[r * 16 + j] += lds[w][lane][j];
        }
        __syncthreads();
    }
    if (wid == 0) {
        if (act) {
            u32 wd[16];
#pragma unroll
            for (int q = 0; q < 16; ++q) wd[q] = pack2(acc[2 * q], acc[2 * q + 1]);
            uint4* dst = reinterpret_cast<uint4*>(out + (size_t)p * 32);
            uint4 v;
            v.x = wd[0];  v.y = wd[1];  v.z = wd[2];  v.w = wd[3];  dst[0] = v;
            v.x = wd[4];  v.y = wd[5];  v.z = wd[6];  v.w = wd[7];  dst[1] = v;
            v.x = wd[8];  v.y = wd[9];  v.z = wd[10]; v.w = wd[11]; dst[2] = v;
            v.x = wd[12]; v.y = wd[13]; v.z = wd[14]; v.w = wd[15]; dst[3] = v;
        } else {
#pragma unroll
            for (int o = 0; o < 32; ++o) acc[o] = 0.f;
        }
        float sel1 = 0.f, sel2 = 0.f;
#pragma unroll
        for (int o = 0; o < 32; ++o) {
            float s1 = acc[o], s2 = acc[o] * acc[o];
#pragma unroll
            for (int m = 1; m <= 32; m <<= 1) { s1 += __shfl_xor(s1, m, 64); s2 += __shfl_xor(s2, m, 64); }
            if (lane == o) sel1 = s1;
            if (lane == o + 32) sel2 = s2;
        }
        atomicAdd(&stats[lane], lane < 32 ? sel1 : sel2);
    }
}

// ---------------- sparse conv on bf16 activations, k split across 4 waves ----------------
// W addresses wave-uniform (scalar loads); nbr indices prefetched for MLP.
template<int K, int CIN>
__global__ __launch_bounds__(256, 4) void conv_bf(
    const u16* __restrict__ src, const int* __restrict__ nbr,
    const float* __restrict__ W, u16* __restrict__ out,
    float* __restrict__ stats, int M)
{
    int lane = threadIdx.x & 63;
    int wid = __builtin_amdgcn_readfirstlane(threadIdx.x >> 6);
    int p = blockIdx.x * 64 + lane;
    bool act = p < M;
    constexpr int JMAX = (K + 3) / 4;

    float acc[32];
#pragma unroll
    for (int o = 0; o < 32; ++o) acc[o] = 0.f;

    int idxs[JMAX];
#pragma unroll
    for (int j = 0; j < JMAX; ++j) {
        int k = wid + 4 * j;
        idxs[j] = (act && k < K) ? nbr[(size_t)p * K + k] : -1;
    }

#pragma unroll
    for (int j = 0; j < JMAX; ++j) {
        int k = wid + 4 * j;
        if (k >= K) break;
        int idx = idxs[j];
        if (idx >= 0) {
            const uint4* __restrict__ xr = reinterpret_cast<const uint4*>(src + (size_t)idx * CIN);
            const float* __restrict__ wk = W + (size_t)k * CIN * 32;
#pragma unroll
            for (int c0 = 0; c0 < CIN; c0 += 8) {
                uint4 v = xr[c0 / 8];
                float xv[8] = { bflo(v.x), bfhi(v.x), bflo(v.y), bfhi(v.y),
                                bflo(v.z), bfhi(v.z), bflo(v.w), bfhi(v.w) };
#pragma unroll
                for (int c = 0; c < 8; ++c)
#pragma unroll
                    for (int o = 0; o < 32; ++o)
                        acc[o] = fmaf(xv[c], wk[(c0 + c) * 32 + o], acc[o]);
            }
        }
    }
    reduce_store_stats(acc, lane, wid, act, p, out, stats);
}

// ---------------- stem0: fp32 x (N,3) -> bf16 ----------------
__global__ __launch_bounds__(256, 4) void conv_x3(
    const float* __restrict__ src, const int* __restrict__ nbr,
    const float* __restrict__ W, u16* __restrict__ out,
    float* __restrict__ stats, int M)
{
    constexpr int K = 27;
    int lane = threadIdx.x & 63;
    int wid = __builtin_amdgcn_readfirstlane(threadIdx.x >> 6);
    int p = blockIdx.x * 64 + lane;
    bool act = p < M;
    constexpr int JMAX = 7;

    float acc[32];
#pragma unroll
    for (int o = 0; o < 32; ++o) acc[o] = 0.f;

    int idxs[JMAX];
#pragma unroll
    for (int j = 0; j < JMAX; ++j) {
        int k = wid + 4 * j;
        idxs[j] = (act && k < K) ? nbr[(size_t)p * K + k] : -1;
    }
#pragma unroll
    for (int j = 0; j < JMAX; ++j) {
        int k = wid + 4 * j;
        if (k >= K) break;
        int idx = idxs[j];
        if (idx >= 0) {
            const float* __restrict__ xr = src + (size_t)idx * 3;
            const float* __restrict__ wk = W + (size_t)k * 3 * 32;
            float x0 = xr[0], x1 = xr[1], x2 = xr[2];
#pragma unroll
            for (int o = 0; o < 32; ++o) {
                float s = fmaf(x0, wk[o], 0.f);
                s = fmaf(x1, wk[32 + o], s);
                acc[o] += fmaf(x2, wk[64 + o], s);
            }
        }
    }
    reduce_store_stats(acc, lane, wid, act, p, out, stats);
}

// ---------------- 1x1 ds conv (cat 64ch -> 32), channels split across waves ----------------
__global__ __launch_bounds__(256, 4) void conv_ds64(
    const u16* __restrict__ src, const float* __restrict__ W,
    u16* __restrict__ out, float* __restrict__ stats, int M)
{
    int lane = threadIdx.x & 63;
    int wid = __builtin_amdgcn_readfirstlane(threadIdx.x >> 6);
    int p = blockIdx.x * 64 + lane;
    bool act = p < M;

    float acc[32];
#pragma unroll
    for (int o = 0; o < 32; ++o) acc[o] = 0.f;

    if (act) {
        const uint4* __restrict__ xr = reinterpret_cast<const uint4*>(src + (size_t)p * 64 + wid * 16);
        const float* __restrict__ wk = W + wid * 16 * 32;   // wave-uniform
#pragma unroll
        for (int h = 0; h < 2; ++h) {
            uint4 v = xr[h];
            float xv[8] = { bflo(v.x), bfhi(v.x), bflo(v.y), bfhi(v.y),
                            bflo(v.z), bfhi(v.z), bflo(v.w), bfhi(v.w) };
#pragma unroll
            for (int c = 0; c < 8; ++c)
#pragma unroll
                for (int o = 0; o < 32; ++o)
                    acc[o] = fmaf(xv[c], wk[(h * 8 + c) * 32 + o], acc[o]);
        }
    }
    reduce_store_stats(acc, lane, wid, act, p, out, stats);
}

// ---------------- bn apply in place on bf16 (thread = 8 channels) ----------------
template<bool RELU>
__global__ __launch_bounds__(256) void bn_apply(
    u16* __restrict__ buf, const float* __restrict__ stats,
    const float* __restrict__ gb, float invM, int total)
{
    int i = blockIdx.x * 256 + threadIdx.x;
    if (i >= total) return;
    int c0 = (i & 3) * 8;
    uint4 v = reinterpret_cast<uint4*>(buf)[i];
    u32 w[4] = { v.x, v.y, v.z, v.w };
    u32 r[4];
#pragma unroll
    for (int q = 0; q < 4; ++q) {
        int c = c0 + 2 * q;
        float mu0 = stats[c] * invM;
        float var0 = fmaxf(stats[32 + c] * invM - mu0 * mu0, 0.f);
        float a0 = gb[c] * rsqrtf(var0 + 1e-5f), b0 = gb[32 + c] - mu0 * a0;
        float mu1 = stats[c + 1] * invM;
        float var1 = fmaxf(stats[32 + c + 1] * invM - mu1 * mu1, 0.f);
        float a1 = gb[c + 1] * rsqrtf(var1 + 1e-5f), b1 = gb[32 + c + 1] - mu1 * a1;
        float y0 = fmaf(a0, bflo(w[q]), b0);
        float y1 = fmaf(a1, bfhi(w[q]), b1);
        if (RELU) { y0 = fmaxf(y0, 0.f); y1 = fmaxf(y1, 0.f); }
        r[q] = pack2(y0, y1);
    }
    uint4 o; o.x = r[0]; o.y = r[1]; o.z = r[2]; o.w = r[3];
    reinterpret_cast<uint4*>(buf)[i] = o;
}

// bn+relu(u raw) -> cat[:,0:32]; copy x0 -> cat[:,32:64]
__global__ __launch_bounds__(256) void bnrelu_cat(
    const u16* __restrict__ u, const u16* __restrict__ x0,
    u16* __restrict__ cat, const float* __restrict__ stats,
    const float* __restrict__ gb, float invM, int total)
{
    int i = blockIdx.x * 256 + threadIdx.x;
    if (i >= total) return;
    int p = i >> 2, j = i & 2 * 2 - 1;   // j = i & 3
    int c0 = j * 8;
    uint4 v = *reinterpret_cast<const uint4*>(u + (size_t)p * 32 + c0);
    u32 w[4] = { v.x, v.y, v.z, v.w };
    u32 r[4];
#pragma unroll
    for (int q = 0; q < 4; ++q) {
        int c = c0 + 2 * q;
        float mu0 = stats[c] * invM;
        float var0 = fmaxf(stats[32 + c] * invM - mu0 * mu0, 0.f);
        float a0 = gb[c] * rsqrtf(var0 + 1e-5f), b0 = gb[32 + c] - mu0 * a0;
        float mu1 = stats[c + 1] * invM;
        float var1 = fmaxf(stats[32 + c + 1] * invM - mu1 * mu1, 0.f);
        float a1 = gb[c + 1] * rsqrtf(var1 + 1e-5f), b1 = gb[32 + c + 1] - mu1 * a1;
        float y0 = fmaxf(fmaf(a0, bflo(w[q]), b0), 0.f);
        float y1 = fmaxf(fmaf(a1, bfhi(w[q]), b1), 0.f);
        r[q] = pack2(y0, y1);
    }
    uint4 o; o.x = r[0]; o.y = r[1]; o.z = r[2]; o.w = r[3];
    *reinterpret_cast<uint4*>(cat + (size_t)p * 64 + c0) = o;
    uint4 cp = *reinterpret_cast<const uint4*>(x0 + (size_t)p * 32 + c0);
    *reinterpret_cast<uint4*>(cat + (size_t)p * 64 + 32 + c0) = cp;
}

// ---------------- attention ----------------
// att layout (floats): [0]=max (uint-encoded), [1]=S, [2..33]=z, [34..65]=ctx
__device__ __forceinline__ void load_row32(const u16* __restrict__ base, int p, float (&nv)[32])
{
    const uint4* xr = reinterpret_cast<const uint4*>(base + (size_t)p * 32);
#pragma unroll
    for (int q = 0; q < 4; ++q) {
        uint4 v = xr[q];
        nv[q * 8 + 0] = bflo(v.x); nv[q * 8 + 1] = bfhi(v.x);
        nv[q * 8 + 2] = bflo(v.y); nv[q * 8 + 3] = bfhi(v.y);
        nv[q * 8 + 4] = bflo(v.z); nv[q * 8 + 5] = bfhi(v.z);
        nv[q * 8 + 6] = bflo(v.w); nv[q * 8 + 7] = bfhi(v.w);
    }
}

__global__ __launch_bounds__(256) void att_logits(
    const u16* __restrict__ net, const float* __restrict__ wi,
    const float* __restrict__ bi, float* __restrict__ lbuf,
    u32* __restrict__ mx, int M)
{
    int p = blockIdx.x * 256 + threadIdx.x;
    float l = -3.0e38f;
    if (p < M) {
        float nv[32];
        load_row32(net, p, nv);
        float s = bi[0];
#pragma unroll
        for (int c = 0; c < 32; ++c) s = fmaf(nv[c], wi[c], s);
        lbuf[p] = s;
        l = s;
    }
#pragma unroll
    for (int m = 1; m <= 32; m <<= 1) l = fmaxf(l, __shfl_xor(l, m, 64));
    if ((threadIdx.x & 63) == 0) {
        u32 b = __float_as_uint(l);
        u32 e = (b & 0x80000000u) ? ~b : (b | 0x80000000u);
        atomicMax(mx, e);
    }
}

__global__ __launch_bounds__(256) void att_accum(
    const u16* __restrict__ net, const float* __restrict__ lbuf,
    float* __restrict__ att, int M)
{
    int p = blockIdx.x * 256 + threadIdx.x;
    int lane = threadIdx.x & 63, wid = threadIdx.x >> 6;
    u32 um = __float_as_uint(att[0]);
    float mx = (um & 0x80000000u) ? __uint_as_float(um ^ 0x80000000u) : __uint_as_float(~um);
    float w = 0.f;
    float nv[32];
#pragma unroll
    for (int c = 0; c < 32; ++c) nv[c] = 0.f;
    if (p < M) {
        w = expf(lbuf[p] - mx);
        load_row32(net, p, nv);
    }
    float sel = 0.f;
#pragma unroll
    for (int c = 0; c < 32; ++c) {
        float s = w * nv[c];
#pragma unroll
        for (int m = 1; m <= 32; m <<= 1) s += __shfl_xor(s, m, 64);
        if (lane == c) sel = s;
    }
    {
        float s = w;
#pragma unroll
        for (int m = 1; m <= 32; m <<= 1) s += __shfl_xor(s, m, 64);
        if (lane == 32) sel = s;
    }
    __shared__ float red[4][33];
    if (lane < 33) red[wid][lane] = sel;
    __syncthreads();
    if (wid == 0 && lane < 33) {
        float t = red[0][lane] + red[1][lane] + red[2][lane] + red[3][lane];
        atomicAdd(lane < 32 ? &att[2 + lane] : &att[1], t);
    }
}

__global__ void att_ctx_k(const float* __restrict__ wk, const float* __restrict__ bk,
                          float* __restrict__ att)
{
    int o = threadIdx.x;
    if (o >= 32) return;
    float invS = 1.0f / att[1];
    float s = bk[o];
#pragma unroll
    for (int c = 0; c < 32; ++c) s = fmaf(att[2 + c] * invS, wk[c * 32 + o], s);
    att[34 + o] = s;
}

// v = (net@wv+bv)*ctx ; r = relu(v@wo + bo + d)
__global__ __launch_bounds__(256) void att_out_res(
    const u16* __restrict__ net, const u16* __restrict__ d,
    const float* __restrict__ wv, const float* __restrict__ bv,
    const float* __restrict__ wo, const float* __restrict__ bo,
    const float* __restrict__ att, u16* __restrict__ r, int M)
{
    int p = blockIdx.x * 256 + threadIdx.x;
    if (p >= M) return;
    float nv[32];
    load_row32(net, p, nv);
    float vv[32];
#pragma unroll
    for (int o = 0; o < 32; ++o) {
        float s = bv[o];
#pragma unroll
        for (int c = 0; c < 32; ++c) s = fmaf(nv[c], wv[c * 32 + o], s);
        vv[o] = s * att[34 + o];
    }
    float dv[32];
    load_row32(d, p, dv);
    u32 wd[16];
#pragma unroll
    for (int q = 0; q < 16; ++q) {
        float y[2];
#pragma unroll
        for (int t = 0; t < 2; ++t) {
            int oo = 2 * q + t;
            float s = bo[oo];
#pragma unroll
            for (int o = 0; o < 32; ++o) s = fmaf(vv[o], wo[o * 32 + oo], s);
            y[t] = fmaxf(s + dv[oo], 0.f);
        }
        wd[q] = pack2(y[0], y[1]);
    }
    uint4* dst = reinterpret_cast<uint4*>(r + (size_t)p * 32);
    uint4 v;
    v.x = wd[0];  v.y = wd[1];  v.z = wd[2];  v.w = wd[3];  dst[0] = v;
    v.x = wd[4];  v.y = wd[5];  v.z = wd[6];  v.w = wd[7];  dst[1] = v;
    v.x = wd[8];  v.y = wd[9];  v.z = wd[10]; v.w = wd[11]; dst[2] = v;
    v.x = wd[12]; v.y = wd[13]; v.z = wd[14]; v.w = wd[15]; dst[3] = v;
}

// ---------------- final: y = relu(bn(net2) + bn(ds)); out = y@Wcls + bcls (fp32 out) ----------------
__global__ __launch_bounds__(256) void final_cls(
    const u16* __restrict__ net2, const u16* __restrict__ dsr,
    const float* __restrict__ st7, const float* __restrict__ st8,
    const float* __restrict__ gb7, const float* __restrict__ gb8,
    const float* __restrict__ wcls, const float* __restrict__ bcls,
    float* __restrict__ outp, float invM, int M)
{
    int p = blockIdx.x * 256 + threadIdx.x;
    if (p >= M) return;
    float nv[32], dv[32];
    load_row32(net2, p, nv);
    load_row32(dsr, p, dv);
    float y[32];
#pragma unroll
    for (int c = 0; c < 32; ++c) {
        float mu1 = st7[c] * invM;
        float var1 = fmaxf(st7[32 + c] * invM - mu1 * mu1, 0.f);
        float a1 = gb7[c] * rsqrtf(var1 + 1e-5f);
        float b1 = gb7[32 + c] - mu1 * a1;
        float mu2 = st8[c] * invM;
        float var2 = fmaxf(st8[32 + c] * invM - mu2 * mu2, 0.f);
        float a2 = gb8[c] * rsqrtf(var2 + 1e-5f);
        float b2 = gb8[32 + c] - mu2 * a2;
        float t = fmaf(a1, nv[c], b1) + fmaf(a2, dv[c], b2);
        y[c] = fmaxf(t, 0.f);
    }
#pragma unroll
    for (int j = 0; j < NCLSS; ++j) {
        float s = bcls[j];
#pragma unroll
        for (int c = 0; c < 32; ++c) s = fmaf(y[c], wcls[c * NCLSS + j], s);
        outp[(size_t)p * NCLSS + j] = s;
    }
}

// ---------------- host ----------------
extern "C" void kernel_launch(void* const* d_in, const int* in_sizes, int n_in,
                              void* d_out, int out_size, void* d_ws, size_t ws_size,
                              hipStream_t stream)
{
    char* wsb = (char*)d_ws;

    // byte-offset workspace layout (bf16 activations)
    float* ST  = (float*)wsb;                 // 642 floats: 9*64 stats + 66 att
    float* ATT = ST + 576;
    float* L   = (float*)(wsb + 4096);        // N1 logits fp32
    u16* A = (u16*)(wsb + 65536);             // N*32 bf16  (7,680,000 B each)
    u16* B = (u16*)(wsb + 65536 + 7680000ull);
    u16* C = (u16*)(wsb + 65536 + 2 * 7680000ull);            // N1*32 (960,000 B)
    u16* D = (u16*)(wsb + 65536 + 2 * 7680000ull + 960000ull);
    u16* E = (u16*)(wsb + 65536 + 2 * 7680000ull + 2 * 960000ull);
    u16* F = (u16*)(wsb + 65536 + 2 * 7680000ull + 3 * 960000ull);          // cat N*64
    u16* G = (u16*)(wsb + 65536 + 2 * 7680000ull + 3 * 960000ull + 15360000ull); // net2 N*32

    // inputs (fp32 per reference dtypes)
    const float* X        = (const float*)d_in[0];
    const float* Wstem0   = (const float*)d_in[1];
    const float* gb_stem0 = (const float*)d_in[2];
    const float* Wstem1   = (const float*)d_in[3];
    const float* gb_stem1 = (const float*)d_in[4];
    const float* Wdown    = (const float*)d_in[5];
    const float* gb_down  = (const float*)d_in[6];
    const float* Wres1    = (const float*)d_in[7];
    const float* gb_res1  = (const float*)d_in[8];
    const float* Wres2    = (const float*)d_in[9];
    const float* gb_res2  = (const float*)d_in[10];
    const float* wi = (const float*)d_in[11];
    const float* bi = (const float*)d_in[12];
    const float* wk = (const float*)d_in[13];
    const float* bk = (const float*)d_in[14];
    const float* wv = (const float*)d_in[15];
    const float* bv = (const float*)d_in[16];
    const float* wo = (const float*)d_in[17];
    const float* bo = (const float*)d_in[18];
    const float* Wup      = (const float*)d_in[19];
    const float* gb_up    = (const float*)d_in[20];
    const float* Wfuse1   = (const float*)d_in[21];
    const float* gb_fuse1 = (const float*)d_in[22];
    const float* Wfuse2   = (const float*)d_in[23];
    const float* gb_fuse2 = (const float*)d_in[24];
    const float* Wds      = (const float*)d_in[25];
    const float* gb_ds    = (const float*)d_in[26];
    const float* Wcls     = (const float*)d_in[27];
    const float* bcls     = (const float*)d_in[28];

    const int* nbr0     = (const int*)d_in[29];
    const int* nbr_down = (const int*)d_in[30];
    const int* nbr1     = (const int*)d_in[31];
    const int* nbr_up   = (const int*)d_in[32];

    const float invN  = 1.0f / (float)NPTS;
    const float invN1 = 1.0f / (float)N1PTS;

    hipMemsetAsync((void*)ST, 0, 642 * sizeof(float), stream);

    const int gKN   = cdiv(NPTS, 64);            // 1875 blocks (4 waves)
    const int gKN1  = cdiv(N1PTS, 64);           // 235
    const int gBN   = cdiv(NPTS * 4, 256);       // 1875 (8ch/thread)
    const int gBN1  = cdiv(N1PTS * 4, 256);      // 235
    const int gN1p  = cdiv(N1PTS, 256);          // 59
    const int gN    = cdiv(NPTS, 256);           // 469

    // stem
    hipLaunchKernelGGL(conv_x3, dim3(gKN), dim3(256), 0, stream,
                       X, nbr0, Wstem0, A, ST + 0 * 64, NPTS);
    hipLaunchKernelGGL((bn_apply<true>), dim3(gBN), dim3(256), 0, stream,
                       A, ST + 0 * 64, gb_stem0, invN, NPTS * 4);
    hipLaunchKernelGGL((conv_bf<27, 32>), dim3(gKN), dim3(256), 0, stream,
                       A, nbr0, Wstem1, B, ST + 1 * 64, NPTS);
    hipLaunchKernelGGL((bn_apply<true>), dim3(gBN), dim3(256), 0, stream,
                       B, ST + 1 * 64, gb_stem1, invN, NPTS * 4);   // B = x0

    // downsample
    hipLaunchKernelGGL((conv_bf<8, 32>), dim3(gKN1), dim3(256), 0, stream,
                       B, nbr_down, Wdown, C, ST + 2 * 64, N1PTS);
    hipLaunchKernelGGL((bn_apply<true>), dim3(gBN1), dim3(256), 0, stream,
                       C, ST + 2 * 64, gb_down, invN1, N1PTS * 4);  // C = d

    // residual block convs
    hipLaunchKernelGGL((conv_bf<27, 32>), dim3(gKN1), dim3(256), 0, stream,
                       C, nbr1, Wres1, D, ST + 3 * 64, N1PTS);
    hipLaunchKernelGGL((bn_apply<true>), dim3(gBN1), dim3(256), 0, stream,
                       D, ST + 3 * 64, gb_res1, invN1, N1PTS * 4);
    hipLaunchKernelGGL((conv_bf<27, 32>), dim3(gKN1), dim3(256), 0, stream,
                       D, nbr1, Wres2, E, ST + 4 * 64, N1PTS);
    hipLaunchKernelGGL((bn_apply<false>), dim3(gBN1), dim3(256), 0, stream,
                       E, ST + 4 * 64, gb_res2, invN1, N1PTS * 4);  // E = net

    // attention + residual add (writes r into D)
    hipLaunchKernelGGL(att_logits, dim3(gN1p), dim3(256), 0, stream,
                       E, wi, bi, L, (u32*)ATT, N1PTS);
    hipLaunchKernelGGL(att_accum, dim3(gN1p), dim3(256), 0, stream, E, L, ATT, N1PTS);
    hipLaunchKernelGGL(att_ctx_k, dim3(1), dim3(64), 0, stream, wk, bk, ATT);
    hipLaunchKernelGGL(att_out_res, dim3(gN1p), dim3(256), 0, stream,
                       E, C, wv, bv, wo, bo, ATT, D, N1PTS);        // D = r

    // upsample + cat
    hipLaunchKernelGGL((conv_bf<8, 32>), dim3(gKN), dim3(256), 0, stream,
                       D, nbr_up, Wup, A, ST + 5 * 64, NPTS);
    hipLaunchKernelGGL(bnrelu_cat, dim3(gBN), dim3(256), 0, stream,
                       A, B, F, ST + 5 * 64, gb_up, invN, NPTS * 4); // F = cat

    // fuse residual block: ds first, then fuse1/fuse2
    hipLaunchKernelGGL(conv_ds64, dim3(gKN), dim3(256), 0, stream,
                       F, Wds, B, ST + 8 * 64, NPTS);                // B = ds raw
    hipLaunchKernelGGL((conv_bf<27, 64>), dim3(gKN), dim3(256), 0, stream,
                       F, nbr0, Wfuse1, A, ST + 6 * 64, NPTS);
    hipLaunchKernelGGL((bn_apply<true>), dim3(gBN), dim3(256), 0, stream,
                       A, ST + 6 * 64, gb_fuse1, invN, NPTS * 4);
    hipLaunchKernelGGL((conv_bf<27, 32>), dim3(gKN), dim3(256), 0, stream,
                       A, nbr0, Wfuse2, G, ST + 7 * 64, NPTS);       // G = net2 raw

    // final fuse + classifier
    hipLaunchKernelGGL(final_cls, dim3(gN), dim3(256), 0, stream,
                       G, B, ST + 7 * 64, ST + 8 * 64, gb_fuse2, gb_ds,
                       Wcls, bcls, (float*)d_out, invN, NPTS);
}

// Round 6
// 695.108 us; speedup vs baseline: 10.8613x; 1.3193x over previous
//
#include <hip/hip_runtime.h>

typedef unsigned int u32;
typedef unsigned short u16;

#define NPTS 120000
#define N1PTS 15000
#define NCLSS 17

static inline int cdiv(int a, int b) { return (a + b - 1) / b; }

typedef __attribute__((ext_vector_type(8))) short bf16x8;
typedef __attribute__((ext_vector_type(4))) float f32x4;

// bf16 helpers (storage-only bf16; math fp32)
__device__ __forceinline__ float bflo(u32 u) { return __uint_as_float(u << 16); }
__device__ __forceinline__ float bfhi(u32 u) { return __uint_as_float(u & 0xFFFF0000u); }
__device__ __forceinline__ u32 f2bf(float f) {   // RNE
    u32 u = __float_as_uint(f);
    return (u + 0x7FFFu + ((u >> 16) & 1u)) >> 16;
}
__device__ __forceinline__ u32 pack2(float a, float b) { return f2bf(a) | (f2bf(b) << 16); }

// ---------------- weight -> B-fragment conversion (hi/lo bf16 split) ----------------
// dst layout: uint4[((s*2 + tile)*2 + h)*64 + lane], s = k*CPS + (c-chunk), tile = o-half,
// h = 0 hi / 1 lo. Lane holds B[k = (lane>>4)*8 + j][col = lane&15] (j=0..7 packed LE).
struct WbArgs {
    const float* src[8];
    uint4* dst[8];
    int CPS[8];    // CIN/32
    int KS2[8];    // K*CPS*2
};

__global__ __launch_bounds__(64) void convert_wb(WbArgs a) {
    int j = blockIdx.y;
    int s2 = blockIdx.x;
    if (s2 >= a.KS2[j]) return;
    int lane = threadIdx.x;
    int s = s2 >> 1, tile = s2 & 1;
    int CPS = a.CPS[j];
    int CIN = CPS * 32;
    int k = s / CPS, c0 = (s % CPS) * 32;
    int c = c0 + (lane >> 4) * 8;
    int o = tile * 16 + (lane & 15);
    const float* w = a.src[j] + ((size_t)k * CIN + c) * 32 + o;
    u32 hw[4], lw[4];
#pragma unroll
    for (int q = 0; q < 4; ++q) {
        float w0 = w[(2 * q) * 32], w1 = w[(2 * q + 1) * 32];
        u32 h0 = f2bf(w0), h1 = f2bf(w1);
        float r0 = w0 - __uint_as_float(h0 << 16);
        float r1 = w1 - __uint_as_float(h1 << 16);
        hw[q] = h0 | (h1 << 16);
        lw[q] = f2bf(r0) | (f2bf(r1) << 16);
    }
    uint4 hv; hv.x = hw[0]; hv.y = hw[1]; hv.z = hw[2]; hv.w = hw[3];
    uint4 lv; lv.x = lw[0]; lv.y = lw[1]; lv.z = lw[2]; lv.w = lw[3];
    a.dst[j][(size_t)(s2 * 2 + 0) * 64 + lane] = hv;
    a.dst[j][(size_t)(s2 * 2 + 1) * 64 + lane] = lv;
}

// ---------------- MFMA sparse conv ----------------
// Wave = 16 points x 32 outputs. Per k-slice (K=32 channels): A-frag = gathered bf16
// rows (lane: row = lane&15, ch = (lane>>4)*8..+7 -> one uint4), B-frag = prepacked W.
// acc = mfma(a, b_hi, acc); acc = mfma(a, b_lo, acc)  (weight hi/lo split, ~fp32 W).
template<int K, int CIN, bool IDENT>
__global__ __launch_bounds__(256, 6) void conv_mfma(
    const u16* __restrict__ src, const int* __restrict__ nbr,
    const uint4* __restrict__ wb, u16* __restrict__ out,
    float* __restrict__ stats, int M)
{
    constexpr int CPS = CIN / 32;
    constexpr int KS = K * CPS;
    int lane = threadIdx.x & 63;
    int wid = threadIdx.x >> 6;
    int p0 = blockIdx.x * 64 + wid * 16;
    int row = lane & 15;
    int hi4 = lane >> 4;
    int p = p0 + row;
    bool rowok = p < M;
    const size_t nbase = (size_t)p * K;

    f32x4 acc0 = {0.f, 0.f, 0.f, 0.f};
    f32x4 acc1 = {0.f, 0.f, 0.f, 0.f};
    const uint4 z4 = {0u, 0u, 0u, 0u};

#pragma unroll 2
    for (int s = 0; s < KS; ++s) {
        int k = (CPS == 1) ? s : (s >> 1);
        int c0 = (CPS == 1) ? 0 : ((s & 1) << 5);
        int idx = -1;
        if (rowok) idx = IDENT ? p : nbr[nbase + k];
        uint4 av = z4;
        if (idx >= 0)
            av = reinterpret_cast<const uint4*>(src + (size_t)idx * CIN + c0)[hi4];
        bf16x8 a = __builtin_bit_cast(bf16x8, av);
        const uint4* bp = wb + (size_t)s * 256 + lane;
        bf16x8 b0h = __builtin_bit_cast(bf16x8, bp[0]);
        bf16x8 b0l = __builtin_bit_cast(bf16x8, bp[64]);
        bf16x8 b1h = __builtin_bit_cast(bf16x8, bp[128]);
        bf16x8 b1l = __builtin_bit_cast(bf16x8, bp[192]);
        acc0 = __builtin_amdgcn_mfma_f32_16x16x32_bf16(a, b0h, acc0, 0, 0, 0);
        acc0 = __builtin_amdgcn_mfma_f32_16x16x32_bf16(a, b0l, acc0, 0, 0, 0);
        acc1 = __builtin_amdgcn_mfma_f32_16x16x32_bf16(a, b1h, acc1, 0, 0, 0);
        acc1 = __builtin_amdgcn_mfma_f32_16x16x32_bf16(a, b1l, acc1, 0, 0, 0);
    }

    // store: lane holds D[point = hi4*4 + r][o = tile*16 + (lane&15)]
#pragma unroll
    for (int r = 0; r < 4; ++r) {
        int pp = p0 + hi4 * 4 + r;
        if (pp < M) {
            out[(size_t)pp * 32 + (lane & 15)] = (u16)f2bf(acc0[r]);
            out[(size_t)pp * 32 + 16 + (lane & 15)] = (u16)f2bf(acc1[r]);
        }
    }

    // bn stats: per-col sum + sumsq over the wave's 16 points, then block combine
    float s0 = 0.f, q0 = 0.f, s1 = 0.f, q1 = 0.f;
#pragma unroll
    for (int r = 0; r < 4; ++r) {
        s0 += acc0[r]; q0 += acc0[r] * acc0[r];
        s1 += acc1[r]; q1 += acc1[r] * acc1[r];
    }
#pragma unroll
    for (int m = 16; m <= 32; m <<= 1) {
        s0 += __shfl_xor(s0, m, 64); q0 += __shfl_xor(q0, m, 64);
        s1 += __shfl_xor(s1, m, 64); q1 += __shfl_xor(q1, m, 64);
    }
    float val = (lane < 16) ? s0 : (lane < 32) ? s1 : (lane < 48) ? q0 : q1;
    __shared__ float red[4][64];
    red[wid][lane] = val;
    __syncthreads();
    if (wid == 0) {
        float t = red[0][lane] + red[1][lane] + red[2][lane] + red[3][lane];
        atomicAdd(&stats[lane], t);
    }
}

// ---------------- stem0 (CIN=3, fp32 x): scalar path, k split across 4 waves ----------------
__device__ __forceinline__ void reduce_store_stats(
    float (&acc)[32], int lane, int wid, bool act, int p,
    u16* __restrict__ out, float* __restrict__ stats)
{
    __shared__ float lds[3][64][17];
#pragma unroll
    for (int r = 0; r < 2; ++r) {
        if (wid > 0) {
#pragma unroll
            for (int j = 0; j < 16; ++j) lds[wid - 1][lane][j] = acc[r * 16 + j];
        }
        __syncthreads();
        if (wid == 0) {
#pragma unroll
            for (int w = 0; w < 3; ++w)
#pragma unroll
                for (int j = 0; j < 16; ++j) acc[r * 16 + j] += lds[w][lane][j];
        }
        __syncthreads();
    }
    if (wid == 0) {
        if (act) {
            u32 wd[16];
#pragma unroll
            for (int q = 0; q < 16; ++q) wd[q] = pack2(acc[2 * q], acc[2 * q + 1]);
            uint4* dst = reinterpret_cast<uint4*>(out + (size_t)p * 32);
            uint4 v;
            v.x = wd[0];  v.y = wd[1];  v.z = wd[2];  v.w = wd[3];  dst[0] = v;
            v.x = wd[4];  v.y = wd[5];  v.z = wd[6];  v.w = wd[7];  dst[1] = v;
            v.x = wd[8];  v.y = wd[9];  v.z = wd[10]; v.w = wd[11]; dst[2] = v;
            v.x = wd[12]; v.y = wd[13]; v.z = wd[14]; v.w = wd[15]; dst[3] = v;
        } else {
#pragma unroll
            for (int o = 0; o < 32; ++o) acc[o] = 0.f;
        }
        float sel1 = 0.f, sel2 = 0.f;
#pragma unroll
        for (int o = 0; o < 32; ++o) {
            float s1 = acc[o], s2 = acc[o] * acc[o];
#pragma unroll
            for (int m = 1; m <= 32; m <<= 1) { s1 += __shfl_xor(s1, m, 64); s2 += __shfl_xor(s2, m, 64); }
            if (lane == o) sel1 = s1;
            if (lane == o + 32) sel2 = s2;
        }
        atomicAdd(&stats[lane], lane < 32 ? sel1 : sel2);
    }
}

__global__ __launch_bounds__(256, 4) void conv_x3(
    const float* __restrict__ src, const int* __restrict__ nbr,
    const float* __restrict__ W, u16* __restrict__ out,
    float* __restrict__ stats, int M)
{
    constexpr int K = 27;
    int lane = threadIdx.x & 63;
    int wid = __builtin_amdgcn_readfirstlane(threadIdx.x >> 6);
    int p = blockIdx.x * 64 + lane;
    bool act = p < M;
    constexpr int JMAX = 7;

    float acc[32];
#pragma unroll
    for (int o = 0; o < 32; ++o) acc[o] = 0.f;

    int idxs[JMAX];
#pragma unroll
    for (int j = 0; j < JMAX; ++j) {
        int k = wid + 4 * j;
        idxs[j] = (act && k < K) ? nbr[(size_t)p * K + k] : -1;
    }
#pragma unroll
    for (int j = 0; j < JMAX; ++j) {
        int k = wid + 4 * j;
        if (k >= K) break;
        int idx = idxs[j];
        if (idx >= 0) {
            const float* __restrict__ xr = src + (size_t)idx * 3;
            const float* __restrict__ wk = W + (size_t)k * 3 * 32;
            float x0 = xr[0], x1 = xr[1], x2 = xr[2];
#pragma unroll
            for (int o = 0; o < 32; ++o) {
                float s = fmaf(x0, wk[o], 0.f);
                s = fmaf(x1, wk[32 + o], s);
                acc[o] += fmaf(x2, wk[64 + o], s);
            }
        }
    }
    reduce_store_stats(acc, lane, wid, act, p, out, stats);
}

// ---------------- bn apply in place on bf16 (thread = 8 channels) ----------------
template<bool RELU>
__global__ __launch_bounds__(256) void bn_apply(
    u16* __restrict__ buf, const float* __restrict__ stats,
    const float* __restrict__ gb, float invM, int total)
{
    int i = blockIdx.x * 256 + threadIdx.x;
    if (i >= total) return;
    int c0 = (i & 3) * 8;
    uint4 v = reinterpret_cast<uint4*>(buf)[i];
    u32 w[4] = { v.x, v.y, v.z, v.w };
    u32 r[4];
#pragma unroll
    for (int q = 0; q < 4; ++q) {
        int c = c0 + 2 * q;
        float mu0 = stats[c] * invM;
        float var0 = fmaxf(stats[32 + c] * invM - mu0 * mu0, 0.f);
        float a0 = gb[c] * rsqrtf(var0 + 1e-5f), b0 = gb[32 + c] - mu0 * a0;
        float mu1 = stats[c + 1] * invM;
        float var1 = fmaxf(stats[32 + c + 1] * invM - mu1 * mu1, 0.f);
        float a1 = gb[c + 1] * rsqrtf(var1 + 1e-5f), b1 = gb[32 + c + 1] - mu1 * a1;
        float y0 = fmaf(a0, bflo(w[q]), b0);
        float y1 = fmaf(a1, bfhi(w[q]), b1);
        if (RELU) { y0 = fmaxf(y0, 0.f); y1 = fmaxf(y1, 0.f); }
        r[q] = pack2(y0, y1);
    }
    uint4 o; o.x = r[0]; o.y = r[1]; o.z = r[2]; o.w = r[3];
    reinterpret_cast<uint4*>(buf)[i] = o;
}

// bn+relu(u raw) -> cat[:,0:32]; copy x0 -> cat[:,32:64]
__global__ __launch_bounds__(256) void bnrelu_cat(
    const u16* __restrict__ u, const u16* __restrict__ x0,
    u16* __restrict__ cat, const float* __restrict__ stats,
    const float* __restrict__ gb, float invM, int total)
{
    int i = blockIdx.x * 256 + threadIdx.x;
    if (i >= total) return;
    int p = i >> 2, j = i & 3;
    int c0 = j * 8;
    uint4 v = *reinterpret_cast<const uint4*>(u + (size_t)p * 32 + c0);
    u32 w[4] = { v.x, v.y, v.z, v.w };
    u32 r[4];
#pragma unroll
    for (int q = 0; q < 4; ++q) {
        int c = c0 + 2 * q;
        float mu0 = stats[c] * invM;
        float var0 = fmaxf(stats[32 + c] * invM - mu0 * mu0, 0.f);
        float a0 = gb[c] * rsqrtf(var0 + 1e-5f), b0 = gb[32 + c] - mu0 * a0;
        float mu1 = stats[c + 1] * invM;
        float var1 = fmaxf(stats[32 + c + 1] * invM - mu1 * mu1, 0.f);
        float a1 = gb[c + 1] * rsqrtf(var1 + 1e-5f), b1 = gb[32 + c + 1] - mu1 * a1;
        float y0 = fmaxf(fmaf(a0, bflo(w[q]), b0), 0.f);
        float y1 = fmaxf(fmaf(a1, bfhi(w[q]), b1), 0.f);
        r[q] = pack2(y0, y1);
    }
    uint4 o; o.x = r[0]; o.y = r[1]; o.z = r[2]; o.w = r[3];
    *reinterpret_cast<uint4*>(cat + (size_t)p * 64 + c0) = o;
    uint4 cp = *reinterpret_cast<const uint4*>(x0 + (size_t)p * 32 + c0);
    *reinterpret_cast<uint4*>(cat + (size_t)p * 64 + 32 + c0) = cp;
}

// ---------------- attention ----------------
__device__ __forceinline__ void load_row32(const u16* __restrict__ base, int p, float (&nv)[32])
{
    const uint4* xr = reinterpret_cast<const uint4*>(base + (size_t)p * 32);
#pragma unroll
    for (int q = 0; q < 4; ++q) {
        uint4 v = xr[q];
        nv[q * 8 + 0] = bflo(v.x); nv[q * 8 + 1] = bfhi(v.x);
        nv[q * 8 + 2] = bflo(v.y); nv[q * 8 + 3] = bfhi(v.y);
        nv[q * 8 + 4] = bflo(v.z); nv[q * 8 + 5] = bfhi(v.z);
        nv[q * 8 + 6] = bflo(v.w); nv[q * 8 + 7] = bfhi(v.w);
    }
}

__global__ __launch_bounds__(256) void att_logits(
    const u16* __restrict__ net, const float* __restrict__ wi,
    const float* __restrict__ bi, float* __restrict__ lbuf,
    u32* __restrict__ mx, int M)
{
    int p = blockIdx.x * 256 + threadIdx.x;
    float l = -3.0e38f;
    if (p < M) {
        float nv[32];
        load_row32(net, p, nv);
        float s = bi[0];
#pragma unroll
        for (int c = 0; c < 32; ++c) s = fmaf(nv[c], wi[c], s);
        lbuf[p] = s;
        l = s;
    }
#pragma unroll
    for (int m = 1; m <= 32; m <<= 1) l = fmaxf(l, __shfl_xor(l, m, 64));
    if ((threadIdx.x & 63) == 0) {
        u32 b = __float_as_uint(l);
        u32 e = (b & 0x80000000u) ? ~b : (b | 0x80000000u);
        atomicMax(mx, e);
    }
}

__global__ __launch_bounds__(256) void att_accum(
    const u16* __restrict__ net, const float* __restrict__ lbuf,
    float* __restrict__ att, int M)
{
    int p = blockIdx.x * 256 + threadIdx.x;
    int lane = threadIdx.x & 63, wid = threadIdx.x >> 6;
    u32 um = __float_as_uint(att[0]);
    float mx = (um & 0x80000000u) ? __uint_as_float(um ^ 0x80000000u) : __uint_as_float(~um);
    float w = 0.f;
    float nv[32];
#pragma unroll
    for (int c = 0; c < 32; ++c) nv[c] = 0.f;
    if (p < M) {
        w = expf(lbuf[p] - mx);
        load_row32(net, p, nv);
    }
    float sel = 0.f;
#pragma unroll
    for (int c = 0; c < 32; ++c) {
        float s = w * nv[c];
#pragma unroll
        for (int m = 1; m <= 32; m <<= 1) s += __shfl_xor(s, m, 64);
        if (lane == c) sel = s;
    }
    {
        float s = w;
#pragma unroll
        for (int m = 1; m <= 32; m <<= 1) s += __shfl_xor(s, m, 64);
        if (lane == 32) sel = s;
    }
    __shared__ float red[4][33];
    if (lane < 33) red[wid][lane] = sel;
    __syncthreads();
    if (wid == 0 && lane < 33) {
        float t = red[0][lane] + red[1][lane] + red[2][lane] + red[3][lane];
        atomicAdd(lane < 32 ? &att[2 + lane] : &att[1], t);
    }
}

__global__ void att_ctx_k(const float* __restrict__ wk, const float* __restrict__ bk,
                          float* __restrict__ att)
{
    int o = threadIdx.x;
    if (o >= 32) return;
    float invS = 1.0f / att[1];
    float s = bk[o];
#pragma unroll
    for (int c = 0; c < 32; ++c) s = fmaf(att[2 + c] * invS, wk[c * 32 + o], s);
    att[34 + o] = s;
}

__global__ __launch_bounds__(256) void att_out_res(
    const u16* __restrict__ net, const u16* __restrict__ d,
    const float* __restrict__ wv, const float* __restrict__ bv,
    const float* __restrict__ wo, const float* __restrict__ bo,
    const float* __restrict__ att, u16* __restrict__ r, int M)
{
    int p = blockIdx.x * 256 + threadIdx.x;
    if (p >= M) return;
    float nv[32];
    load_row32(net, p, nv);
    float vv[32];
#pragma unroll
    for (int o = 0; o < 32; ++o) {
        float s = bv[o];
#pragma unroll
        for (int c = 0; c < 32; ++c) s = fmaf(nv[c], wv[c * 32 + o], s);
        vv[o] = s * att[34 + o];
    }
    float dv[32];
    load_row32(d, p, dv);
    u32 wd[16];
#pragma unroll
    for (int q = 0; q < 16; ++q) {
        float y[2];
#pragma unroll
        for (int t = 0; t < 2; ++t) {
            int oo = 2 * q + t;
            float s = bo[oo];
#pragma unroll
            for (int o = 0; o < 32; ++o) s = fmaf(vv[o], wo[o * 32 + oo], s);
            y[t] = fmaxf(s + dv[oo], 0.f);
        }
        wd[q] = pack2(y[0], y[1]);
    }
    uint4* dst = reinterpret_cast<uint4*>(r + (size_t)p * 32);
    uint4 v;
    v.x = wd[0];  v.y = wd[1];  v.z = wd[2];  v.w = wd[3];  dst[0] = v;
    v.x = wd[4];  v.y = wd[5];  v.z = wd[6];  v.w = wd[7];  dst[1] = v;
    v.x = wd[8];  v.y = wd[9];  v.z = wd[10]; v.w = wd[11]; dst[2] = v;
    v.x = wd[12]; v.y = wd[13]; v.z = wd[14]; v.w = wd[15]; dst[3] = v;
}

// ---------------- final: y = relu(bn(net2) + bn(ds)); out = y@Wcls + bcls ----------------
__global__ __launch_bounds__(256) void final_cls(
    const u16* __restrict__ net2, const u16* __restrict__ dsr,
    const float* __restrict__ st7, const float* __restrict__ st8,
    const float* __restrict__ gb7, const float* __restrict__ gb8,
    const float* __restrict__ wcls, const float* __restrict__ bcls,
    float* __restrict__ outp, float invM, int M)
{
    int p = blockIdx.x * 256 + threadIdx.x;
    if (p >= M) return;
    float nv[32], dv[32];
    load_row32(net2, p, nv);
    load_row32(dsr, p, dv);
    float y[32];
#pragma unroll
    for (int c = 0; c < 32; ++c) {
        float mu1 = st7[c] * invM;
        float var1 = fmaxf(st7[32 + c] * invM - mu1 * mu1, 0.f);
        float a1 = gb7[c] * rsqrtf(var1 + 1e-5f);
        float b1 = gb7[32 + c] - mu1 * a1;
        float mu2 = st8[c] * invM;
        float var2 = fmaxf(st8[32 + c] * invM - mu2 * mu2, 0.f);
        float a2 = gb8[c] * rsqrtf(var2 + 1e-5f);
        float b2 = gb8[32 + c] - mu2 * a2;
        float t = fmaf(a1, nv[c], b1) + fmaf(a2, dv[c], b2);
        y[c] = fmaxf(t, 0.f);
    }
#pragma unroll
    for (int j = 0; j < NCLSS; ++j) {
        float s = bcls[j];
#pragma unroll
        for (int c = 0; c < 32; ++c) s = fmaf(y[c], wcls[c * NCLSS + j], s);
        outp[(size_t)p * NCLSS + j] = s;
    }
}

// ---------------- host ----------------
extern "C" void kernel_launch(void* const* d_in, const int* in_sizes, int n_in,
                              void* d_out, int out_size, void* d_ws, size_t ws_size,
                              hipStream_t stream)
{
    char* wsb = (char*)d_ws;

    float* ST  = (float*)wsb;                 // 642 floats: 9*64 stats + 66 att
    float* ATT = ST + 576;
    float* L   = (float*)(wsb + 4096);        // N1 logits fp32
    u16* A = (u16*)(wsb + 65536);             // N*32 bf16 (7,680,000 B each)
    u16* B = (u16*)(wsb + 65536 + 7680000ull);
    u16* C = (u16*)(wsb + 65536 + 2 * 7680000ull);            // N1*32 (960,000 B)
    u16* D = (u16*)(wsb + 65536 + 2 * 7680000ull + 960000ull);
    u16* E = (u16*)(wsb + 65536 + 2 * 7680000ull + 2 * 960000ull);
    u16* F = (u16*)(wsb + 65536 + 2 * 7680000ull + 3 * 960000ull);          // cat N*64
    u16* G = (u16*)(wsb + 65536 + 2 * 7680000ull + 3 * 960000ull + 15360000ull); // net2 N*32

    // B-fragment weight buffers (after G)
    size_t wboff = 65536 + 2 * 7680000ull + 3 * 960000ull + 15360000ull + 7680000ull;
    // sizes in bytes: KS2 * 2 * 64 * 16
    auto wbsz = [](int K, int CPS) { return (size_t)K * CPS * 2 * 2 * 64 * 16; };
    uint4* wb_stem1 = (uint4*)(wsb + wboff);                    size_t o1 = wboff + wbsz(27, 1);
    uint4* wb_down  = (uint4*)(wsb + o1);                       size_t o2 = o1 + wbsz(8, 1);
    uint4* wb_res1  = (uint4*)(wsb + o2);                       size_t o3 = o2 + wbsz(27, 1);
    uint4* wb_res2  = (uint4*)(wsb + o3);                       size_t o4 = o3 + wbsz(27, 1);
    uint4* wb_up    = (uint4*)(wsb + o4);                       size_t o5 = o4 + wbsz(8, 1);
    uint4* wb_fuse1 = (uint4*)(wsb + o5);                       size_t o6 = o5 + wbsz(27, 2);
    uint4* wb_fuse2 = (uint4*)(wsb + o6);                       size_t o7 = o6 + wbsz(27, 1);
    uint4* wb_ds    = (uint4*)(wsb + o7);

    // inputs (fp32 per reference dtypes)
    const float* X        = (const float*)d_in[0];
    const float* Wstem0   = (const float*)d_in[1];
    const float* gb_stem0 = (const float*)d_in[2];
    const float* Wstem1   = (const float*)d_in[3];
    const float* gb_stem1 = (const float*)d_in[4];
    const float* Wdown    = (const float*)d_in[5];
    const float* gb_down  = (const float*)d_in[6];
    const float* Wres1    = (const float*)d_in[7];
    const float* gb_res1  = (const float*)d_in[8];
    const float* Wres2    = (const float*)d_in[9];
    const float* gb_res2  = (const float*)d_in[10];
    const float* wi = (const float*)d_in[11];
    const float* bi = (const float*)d_in[12];
    const float* wk = (const float*)d_in[13];
    const float* bk = (const float*)d_in[14];
    const float* wv = (const float*)d_in[15];
    const float* bv = (const float*)d_in[16];
    const float* wo = (const float*)d_in[17];
    const float* bo = (const float*)d_in[18];
    const float* Wup      = (const float*)d_in[19];
    const float* gb_up    = (const float*)d_in[20];
    const float* Wfuse1   = (const float*)d_in[21];
    const float* gb_fuse1 = (const float*)d_in[22];
    const float* Wfuse2   = (const float*)d_in[23];
    const float* gb_fuse2 = (const float*)d_in[24];
    const float* Wds      = (const float*)d_in[25];
    const float* gb_ds    = (const float*)d_in[26];
    const float* Wcls     = (const float*)d_in[27];
    const float* bcls     = (const float*)d_in[28];

    const int* nbr0     = (const int*)d_in[29];
    const int* nbr_down = (const int*)d_in[30];
    const int* nbr1     = (const int*)d_in[31];
    const int* nbr_up   = (const int*)d_in[32];

    const float invN  = 1.0f / (float)NPTS;
    const float invN1 = 1.0f / (float)N1PTS;

    hipMemsetAsync((void*)ST, 0, 642 * sizeof(float), stream);

    // pack all conv weights into MFMA B-fragment layout (hi/lo split)
    {
        WbArgs a;
        a.src[0] = Wstem1; a.dst[0] = wb_stem1; a.CPS[0] = 1; a.KS2[0] = 54;
        a.src[1] = Wdown;  a.dst[1] = wb_down;  a.CPS[1] = 1; a.KS2[1] = 16;
        a.src[2] = Wres1;  a.dst[2] = wb_res1;  a.CPS[2] = 1; a.KS2[2] = 54;
        a.src[3] = Wres2;  a.dst[3] = wb_res2;  a.CPS[3] = 1; a.KS2[3] = 54;
        a.src[4] = Wup;    a.dst[4] = wb_up;    a.CPS[4] = 1; a.KS2[4] = 16;
        a.src[5] = Wfuse1; a.dst[5] = wb_fuse1; a.CPS[5] = 2; a.KS2[5] = 108;
        a.src[6] = Wfuse2; a.dst[6] = wb_fuse2; a.CPS[6] = 1; a.KS2[6] = 54;
        a.src[7] = Wds;    a.dst[7] = wb_ds;    a.CPS[7] = 2; a.KS2[7] = 4;
        hipLaunchKernelGGL(convert_wb, dim3(108, 8), dim3(64), 0, stream, a);
    }

    const int gMN   = cdiv(NPTS, 64);            // 1875 (4 waves x 16 pts)
    const int gMN1  = cdiv(N1PTS, 64);           // 235
    const int gBN   = cdiv(NPTS * 4, 256);
    const int gBN1  = cdiv(N1PTS * 4, 256);
    const int gN1p  = cdiv(N1PTS, 256);
    const int gN    = cdiv(NPTS, 256);

    // stem
    hipLaunchKernelGGL(conv_x3, dim3(gMN), dim3(256), 0, stream,
                       X, nbr0, Wstem0, A, ST + 0 * 64, NPTS);
    hipLaunchKernelGGL((bn_apply<true>), dim3(gBN), dim3(256), 0, stream,
                       A, ST + 0 * 64, gb_stem0, invN, NPTS * 4);
    hipLaunchKernelGGL((conv_mfma<27, 32, false>), dim3(gMN), dim3(256), 0, stream,
                       A, nbr0, wb_stem1, B, ST + 1 * 64, NPTS);
    hipLaunchKernelGGL((bn_apply<true>), dim3(gBN), dim3(256), 0, stream,
                       B, ST + 1 * 64, gb_stem1, invN, NPTS * 4);   // B = x0

    // downsample
    hipLaunchKernelGGL((conv_mfma<8, 32, false>), dim3(gMN1), dim3(256), 0, stream,
                       B, nbr_down, wb_down, C, ST + 2 * 64, N1PTS);
    hipLaunchKernelGGL((bn_apply<true>), dim3(gBN1), dim3(256), 0, stream,
                       C, ST + 2 * 64, gb_down, invN1, N1PTS * 4);  // C = d

    // residual block convs
    hipLaunchKernelGGL((conv_mfma<27, 32, false>), dim3(gMN1), dim3(256), 0, stream,
                       C, nbr1, wb_res1, D, ST + 3 * 64, N1PTS);
    hipLaunchKernelGGL((bn_apply<true>), dim3(gBN1), dim3(256), 0, stream,
                       D, ST + 3 * 64, gb_res1, invN1, N1PTS * 4);
    hipLaunchKernelGGL((conv_mfma<27, 32, false>), dim3(gMN1), dim3(256), 0, stream,
                       D, nbr1, wb_res2, E, ST + 4 * 64, N1PTS);
    hipLaunchKernelGGL((bn_apply<false>), dim3(gBN1), dim3(256), 0, stream,
                       E, ST + 4 * 64, gb_res2, invN1, N1PTS * 4);  // E = net

    // attention + residual add (writes r into D)
    hipLaunchKernelGGL(att_logits, dim3(gN1p), dim3(256), 0, stream,
                       E, wi, bi, L, (u32*)ATT, N1PTS);
    hipLaunchKernelGGL(att_accum, dim3(gN1p), dim3(256), 0, stream, E, L, ATT, N1PTS);
    hipLaunchKernelGGL(att_ctx_k, dim3(1), dim3(64), 0, stream, wk, bk, ATT);
    hipLaunchKernelGGL(att_out_res, dim3(gN1p), dim3(256), 0, stream,
                       E, C, wv, bv, wo, bo, ATT, D, N1PTS);        // D = r

    // upsample + cat
    hipLaunchKernelGGL((conv_mfma<8, 32, false>), dim3(gMN), dim3(256), 0, stream,
                       D, nbr_up, wb_up, A, ST + 5 * 64, NPTS);
    hipLaunchKernelGGL(bnrelu_cat, dim3(gBN), dim3(256), 0, stream,
                       A, B, F, ST + 5 * 64, gb_up, invN, NPTS * 4); // F = cat

    // fuse residual block: ds first, then fuse1/fuse2
    hipLaunchKernelGGL((conv_mfma<1, 64, true>), dim3(gMN), dim3(256), 0, stream,
                       F, (const int*)nullptr, wb_ds, B, ST + 8 * 64, NPTS); // B = ds raw
    hipLaunchKernelGGL((conv_mfma<27, 64, false>), dim3(gMN), dim3(256), 0, stream,
                       F, nbr0, wb_fuse1, A, ST + 6 * 64, NPTS);
    hipLaunchKernelGGL((bn_apply<true>), dim3(gBN), dim3(256), 0, stream,
                       A, ST + 6 * 64, gb_fuse1, invN, NPTS * 4);
    hipLaunchKernelGGL((conv_mfma<27, 32, false>), dim3(gMN), dim3(256), 0, stream,
                       A, nbr0, wb_fuse2, G, ST + 7 * 64, NPTS);     // G = net2 raw

    // final fuse + classifier
    hipLaunchKernelGGL(final_cls, dim3(gN), dim3(256), 0, stream,
                       G, B, ST + 7 * 64, ST + 8 * 64, gb_fuse2, gb_ds,
                       Wcls, bcls, (float*)d_out, invN, NPTS);
}

// Round 7
// 574.506 us; speedup vs baseline: 13.1414x; 1.2099x over previous
//
#include <hip/hip_runtime.h>

typedef unsigned int u32;
typedef unsigned short u16;

#define NPTS 120000
#define N1PTS 15000
#define NCLSS 17

static inline int cdiv(int a, int b) { return (a + b - 1) / b; }

typedef __attribute__((ext_vector_type(8))) short bf16x8;
typedef __attribute__((ext_vector_type(4))) float f32x4;

// bf16 helpers (storage-only bf16; math fp32)
__device__ __forceinline__ float bflo(u32 u) { return __uint_as_float(u << 16); }
__device__ __forceinline__ float bfhi(u32 u) { return __uint_as_float(u & 0xFFFF0000u); }
__device__ __forceinline__ u32 f2bf(float f) {   // RNE
    u32 u = __float_as_uint(f);
    return (u + 0x7FFFu + ((u >> 16) & 1u)) >> 16;
}
__device__ __forceinline__ u32 pack2(float a, float b) { return f2bf(a) | (f2bf(b) << 16); }

// ---------------- nbr transpose: nbrT[k*M + p] = nbr[p*K + k] ----------------
template<int K>
__global__ __launch_bounds__(256) void transpose_nbr(
    const int* __restrict__ nbr, int* __restrict__ nbrT, int M)
{
    __shared__ int tile[256][K + 1];
    int p0 = blockIdx.x * 256;
    int t = threadIdx.x;
    int np = M - p0; if (np > 256) np = 256;
    int total = np * K;
    for (int i = t; i < total; i += 256) {
        int lp = i / K, k = i - lp * K;
        tile[lp][k] = nbr[(size_t)p0 * K + i];
    }
    __syncthreads();
    if (t < np) {
#pragma unroll
        for (int k = 0; k < K; ++k)
            nbrT[(size_t)k * M + p0 + t] = tile[t][k];
    }
}

// ---------------- weight -> B-fragment conversion (hi/lo bf16 split) ----------------
// uint4 index: s*256 + tile*128 + h*64 + lane  (s = k*CPS + c-chunk, tile = o-half, h=0 hi /1 lo)
struct WbArgs {
    const float* src[8];
    uint4* dst[8];
    int CPS[8];
    int KS2[8];    // K*CPS*2
};

__global__ __launch_bounds__(64) void convert_wb(WbArgs a) {
    int j = blockIdx.y;
    int s2 = blockIdx.x;
    if (s2 >= a.KS2[j]) return;
    int lane = threadIdx.x;
    int s = s2 >> 1, tile = s2 & 1;
    int CPS = a.CPS[j];
    int CIN = CPS * 32;
    int k = s / CPS, c0 = (s % CPS) * 32;
    int c = c0 + (lane >> 4) * 8;
    int o = tile * 16 + (lane & 15);
    const float* w = a.src[j] + ((size_t)k * CIN + c) * 32 + o;
    u32 hw[4], lw[4];
#pragma unroll
    for (int q = 0; q < 4; ++q) {
        float w0 = w[(2 * q) * 32], w1 = w[(2 * q + 1) * 32];
        u32 h0 = f2bf(w0), h1 = f2bf(w1);
        float r0 = w0 - __uint_as_float(h0 << 16);
        float r1 = w1 - __uint_as_float(h1 << 16);
        hw[q] = h0 | (h1 << 16);
        lw[q] = f2bf(r0) | (f2bf(r1) << 16);
    }
    uint4 hv; hv.x = hw[0]; hv.y = hw[1]; hv.z = hw[2]; hv.w = hw[3];
    uint4 lv; lv.x = lw[0]; lv.y = lw[1]; lv.z = lw[2]; lv.w = lw[3];
    a.dst[j][(size_t)(s2 * 2 + 0) * 64 + lane] = hv;
    a.dst[j][(size_t)(s2 * 2 + 1) * 64 + lane] = lv;
}

// ---------------- MFMA sparse conv, LDS-staged weights, prefetch pipeline ----------------
// Wave = 16 points x 32 outputs. Block's 4 waves share wb via LDS (double-buffered
// 2-step chunks). nbrT is k-major -> coalesced idx loads. Gathers prefetched 1 chunk ahead.
template<int K, int CIN, bool IDENT>
__global__ __launch_bounds__(256, 6) void conv_mfma(
    const u16* __restrict__ src, const int* __restrict__ nbrT,
    const uint4* __restrict__ wb, u16* __restrict__ out,
    float* __restrict__ stats, int M)
{
    constexpr int CPS = CIN / 32;
    constexpr int KS = K * CPS;
    constexpr int NCH = (KS + 1) / 2;
    __shared__ uint4 wlds[2][512];   // 2 x (2 steps x 256 uint4) = 16 KB
    __shared__ float red[4][64];

    int tid = threadIdx.x;
    int lane = tid & 63, wid = tid >> 6;
    int p0 = blockIdx.x * 64 + wid * 16;
    int row = lane & 15, hi4 = lane >> 4;
    int p = p0 + row;
    bool rowok = p < M;
    const uint4 z4 = {0u, 0u, 0u, 0u};

    f32x4 acc0 = {0.f, 0.f, 0.f, 0.f};
    f32x4 acc1 = {0.f, 0.f, 0.f, 0.f};

    // prologue: stage chunk 0, gather s=0,1
    {
        uint4 a0 = wb[tid], a1 = wb[256 + tid];
        wlds[0][tid] = a0; wlds[0][256 + tid] = a1;
    }
    uint4 av0 = z4, av1 = z4;
    {
        int iA = -1, iB = -1;
        if (rowok) {
            iA = IDENT ? p : nbrT[p];
            if (KS > 1) iB = IDENT ? p : ((CPS == 2) ? iA : nbrT[(size_t)M + p]);
        }
        if (iA >= 0) av0 = reinterpret_cast<const uint4*>(src + (size_t)iA * CIN)[hi4];
        if (KS > 1 && iB >= 0)
            av1 = reinterpret_cast<const uint4*>(src + (size_t)iB * CIN + (CPS == 2 ? 32 : 0))[hi4];
    }

    uint4 wr0 = z4, wr1 = z4;
#pragma unroll 1
    for (int c = 0; c < NCH; ++c) {
        bool last = (c + 1 >= NCH);
        if (!last) {
            wr0 = wb[(size_t)(c + 1) * 512 + tid];
            wr1 = wb[(size_t)(c + 1) * 512 + 256 + tid];
        }
        int nA = -1, nB = -1;
        if (!last && rowok) {
            int s0 = 2 * c + 2;
            int k0 = (CPS == 1) ? s0 : (s0 >> 1);
            nA = IDENT ? p : nbrT[(size_t)k0 * M + p];
            if (s0 + 1 < KS) {
                int k1 = (CPS == 1) ? (s0 + 1) : k0;
                nB = IDENT ? p : ((CPS == 2) ? nA : nbrT[(size_t)k1 * M + p]);
            }
        }
        __syncthreads();   // wlds[c&1] ready for all waves
        uint4 nav0 = z4, nav1 = z4;
        if (nA >= 0) nav0 = reinterpret_cast<const uint4*>(src + (size_t)nA * CIN)[hi4];
        if (nB >= 0) nav1 = reinterpret_cast<const uint4*>(src + (size_t)nB * CIN + (CPS == 2 ? 32 : 0))[hi4];

        const uint4* bl = wlds[c & 1];
        {
            bf16x8 a = __builtin_bit_cast(bf16x8, av0);
            bf16x8 b0h = __builtin_bit_cast(bf16x8, bl[lane]);
            bf16x8 b0l = __builtin_bit_cast(bf16x8, bl[64 + lane]);
            bf16x8 b1h = __builtin_bit_cast(bf16x8, bl[128 + lane]);
            bf16x8 b1l = __builtin_bit_cast(bf16x8, bl[192 + lane]);
            acc0 = __builtin_amdgcn_mfma_f32_16x16x32_bf16(a, b0h, acc0, 0, 0, 0);
            acc0 = __builtin_amdgcn_mfma_f32_16x16x32_bf16(a, b0l, acc0, 0, 0, 0);
            acc1 = __builtin_amdgcn_mfma_f32_16x16x32_bf16(a, b1h, acc1, 0, 0, 0);
            acc1 = __builtin_amdgcn_mfma_f32_16x16x32_bf16(a, b1l, acc1, 0, 0, 0);
        }
        if (2 * c + 1 < KS) {
            bf16x8 a = __builtin_bit_cast(bf16x8, av1);
            bf16x8 b0h = __builtin_bit_cast(bf16x8, bl[256 + lane]);
            bf16x8 b0l = __builtin_bit_cast(bf16x8, bl[320 + lane]);
            bf16x8 b1h = __builtin_bit_cast(bf16x8, bl[384 + lane]);
            bf16x8 b1l = __builtin_bit_cast(bf16x8, bl[448 + lane]);
            acc0 = __builtin_amdgcn_mfma_f32_16x16x32_bf16(a, b0h, acc0, 0, 0, 0);
            acc0 = __builtin_amdgcn_mfma_f32_16x16x32_bf16(a, b0l, acc0, 0, 0, 0);
            acc1 = __builtin_amdgcn_mfma_f32_16x16x32_bf16(a, b1h, acc1, 0, 0, 0);
            acc1 = __builtin_amdgcn_mfma_f32_16x16x32_bf16(a, b1l, acc1, 0, 0, 0);
        }
        if (!last) {
            wlds[(c + 1) & 1][tid] = wr0;
            wlds[(c + 1) & 1][256 + tid] = wr1;
        }
        av0 = nav0; av1 = nav1;
    }

    // store: lane holds D[point = hi4*4 + r][o = tile*16 + (lane&15)]
#pragma unroll
    for (int r = 0; r < 4; ++r) {
        int pp = p0 + hi4 * 4 + r;
        if (pp < M) {
            out[(size_t)pp * 32 + (lane & 15)] = (u16)f2bf(acc0[r]);
            out[(size_t)pp * 32 + 16 + (lane & 15)] = (u16)f2bf(acc1[r]);
        }
    }

    // bn stats
    float s0 = 0.f, q0 = 0.f, s1 = 0.f, q1 = 0.f;
#pragma unroll
    for (int r = 0; r < 4; ++r) {
        s0 += acc0[r]; q0 += acc0[r] * acc0[r];
        s1 += acc1[r]; q1 += acc1[r] * acc1[r];
    }
#pragma unroll
    for (int m = 16; m <= 32; m <<= 1) {
        s0 += __shfl_xor(s0, m, 64); q0 += __shfl_xor(q0, m, 64);
        s1 += __shfl_xor(s1, m, 64); q1 += __shfl_xor(q1, m, 64);
    }
    float val = (lane < 16) ? s0 : (lane < 32) ? s1 : (lane < 48) ? q0 : q1;
    red[wid][lane] = val;
    __syncthreads();
    if (wid == 0) {
        float t = red[0][lane] + red[1][lane] + red[2][lane] + red[3][lane];
        atomicAdd(&stats[lane], t);
    }
}

// ---------------- stem0 (CIN=3, fp32 x): scalar path, k split across 4 waves ----------------
__device__ __forceinline__ void reduce_store_stats(
    float (&acc)[32], int lane, int wid, bool act, int p,
    u16* __restrict__ out, float* __restrict__ stats)
{
    __shared__ float lds[3][64][17];
#pragma unroll
    for (int r = 0; r < 2; ++r) {
        if (wid > 0) {
#pragma unroll
            for (int j = 0; j < 16; ++j) lds[wid - 1][lane][j] = acc[r * 16 + j];
        }
        __syncthreads();
        if (wid == 0) {
#pragma unroll
            for (int w = 0; w < 3; ++w)
#pragma unroll
                for (int j = 0; j < 16; ++j) acc[r * 16 + j] += lds[w][lane][j];
        }
        __syncthreads();
    }
    if (wid == 0) {
        if (act) {
            u32 wd[16];
#pragma unroll
            for (int q = 0; q < 16; ++q) wd[q] = pack2(acc[2 * q], acc[2 * q + 1]);
            uint4* dst = reinterpret_cast<uint4*>(out + (size_t)p * 32);
            uint4 v;
            v.x = wd[0];  v.y = wd[1];  v.z = wd[2];  v.w = wd[3];  dst[0] = v;
            v.x = wd[4];  v.y = wd[5];  v.z = wd[6];  v.w = wd[7];  dst[1] = v;
            v.x = wd[8];  v.y = wd[9];  v.z = wd[10]; v.w = wd[11]; dst[2] = v;
            v.x = wd[12]; v.y = wd[13]; v.z = wd[14]; v.w = wd[15]; dst[3] = v;
        } else {
#pragma unroll
            for (int o = 0; o < 32; ++o) acc[o] = 0.f;
        }
        float sel1 = 0.f, sel2 = 0.f;
#pragma unroll
        for (int o = 0; o < 32; ++o) {
            float s1 = acc[o], s2 = acc[o] * acc[o];
#pragma unroll
            for (int m = 1; m <= 32; m <<= 1) { s1 += __shfl_xor(s1, m, 64); s2 += __shfl_xor(s2, m, 64); }
            if (lane == o) sel1 = s1;
            if (lane == o + 32) sel2 = s2;
        }
        atomicAdd(&stats[lane], lane < 32 ? sel1 : sel2);
    }
}

__global__ __launch_bounds__(256, 4) void conv_x3(
    const float* __restrict__ src, const int* __restrict__ nbrT,
    const float* __restrict__ W, u16* __restrict__ out,
    float* __restrict__ stats, int M)
{
    constexpr int K = 27;
    int lane = threadIdx.x & 63;
    int wid = __builtin_amdgcn_readfirstlane(threadIdx.x >> 6);
    int p = blockIdx.x * 64 + lane;
    bool act = p < M;
    constexpr int JMAX = 7;

    float acc[32];
#pragma unroll
    for (int o = 0; o < 32; ++o) acc[o] = 0.f;

    int idxs[JMAX];
#pragma unroll
    for (int j = 0; j < JMAX; ++j) {
        int k = wid + 4 * j;
        idxs[j] = (act && k < K) ? nbrT[(size_t)k * M + p] : -1;
    }
#pragma unroll
    for (int j = 0; j < JMAX; ++j) {
        int k = wid + 4 * j;
        if (k >= K) break;
        int idx = idxs[j];
        if (idx >= 0) {
            const float* __restrict__ xr = src + (size_t)idx * 3;
            const float* __restrict__ wk = W + (size_t)k * 3 * 32;
            float x0 = xr[0], x1 = xr[1], x2 = xr[2];
#pragma unroll
            for (int o = 0; o < 32; ++o) {
                float s = fmaf(x0, wk[o], 0.f);
                s = fmaf(x1, wk[32 + o], s);
                acc[o] += fmaf(x2, wk[64 + o], s);
            }
        }
    }
    reduce_store_stats(acc, lane, wid, act, p, out, stats);
}

// ---------------- bn apply in place on bf16 (thread = 8 channels) ----------------
template<bool RELU>
__global__ __launch_bounds__(256) void bn_apply(
    u16* __restrict__ buf, const float* __restrict__ stats,
    const float* __restrict__ gb, float invM, int total)
{
    int i = blockIdx.x * 256 + threadIdx.x;
    if (i >= total) return;
    int c0 = (i & 3) * 8;
    uint4 v = reinterpret_cast<uint4*>(buf)[i];
    u32 w[4] = { v.x, v.y, v.z, v.w };
    u32 r[4];
#pragma unroll
    for (int q = 0; q < 4; ++q) {
        int c = c0 + 2 * q;
        float mu0 = stats[c] * invM;
        float var0 = fmaxf(stats[32 + c] * invM - mu0 * mu0, 0.f);
        float a0 = gb[c] * rsqrtf(var0 + 1e-5f), b0 = gb[32 + c] - mu0 * a0;
        float mu1 = stats[c + 1] * invM;
        float var1 = fmaxf(stats[32 + c + 1] * invM - mu1 * mu1, 0.f);
        float a1 = gb[c + 1] * rsqrtf(var1 + 1e-5f), b1 = gb[32 + c + 1] - mu1 * a1;
        float y0 = fmaf(a0, bflo(w[q]), b0);
        float y1 = fmaf(a1, bfhi(w[q]), b1);
        if (RELU) { y0 = fmaxf(y0, 0.f); y1 = fmaxf(y1, 0.f); }
        r[q] = pack2(y0, y1);
    }
    uint4 o; o.x = r[0]; o.y = r[1]; o.z = r[2]; o.w = r[3];
    reinterpret_cast<uint4*>(buf)[i] = o;
}

// bn+relu(u raw) -> cat[:,0:32]; copy x0 -> cat[:,32:64]
__global__ __launch_bounds__(256) void bnrelu_cat(
    const u16* __restrict__ u, const u16* __restrict__ x0,
    u16* __restrict__ cat, const float* __restrict__ stats,
    const float* __restrict__ gb, float invM, int total)
{
    int i = blockIdx.x * 256 + threadIdx.x;
    if (i >= total) return;
    int p = i >> 2, j = i & 3;
    int c0 = j * 8;
    uint4 v = *reinterpret_cast<const uint4*>(u + (size_t)p * 32 + c0);
    u32 w[4] = { v.x, v.y, v.z, v.w };
    u32 r[4];
#pragma unroll
    for (int q = 0; q < 4; ++q) {
        int c = c0 + 2 * q;
        float mu0 = stats[c] * invM;
        float var0 = fmaxf(stats[32 + c] * invM - mu0 * mu0, 0.f);
        float a0 = gb[c] * rsqrtf(var0 + 1e-5f), b0 = gb[32 + c] - mu0 * a0;
        float mu1 = stats[c + 1] * invM;
        float var1 = fmaxf(stats[32 + c + 1] * invM - mu1 * mu1, 0.f);
        float a1 = gb[c + 1] * rsqrtf(var1 + 1e-5f), b1 = gb[32 + c + 1] - mu1 * a1;
        float y0 = fmaxf(fmaf(a0, bflo(w[q]), b0), 0.f);
        float y1 = fmaxf(fmaf(a1, bfhi(w[q]), b1), 0.f);
        r[q] = pack2(y0, y1);
    }
    uint4 o; o.x = r[0]; o.y = r[1]; o.z = r[2]; o.w = r[3];
    *reinterpret_cast<uint4*>(cat + (size_t)p * 64 + c0) = o;
    uint4 cp = *reinterpret_cast<const uint4*>(x0 + (size_t)p * 32 + c0);
    *reinterpret_cast<uint4*>(cat + (size_t)p * 64 + 32 + c0) = cp;
}

// ---------------- attention ----------------
__device__ __forceinline__ void load_row32(const u16* __restrict__ base, int p, float (&nv)[32])
{
    const uint4* xr = reinterpret_cast<const uint4*>(base + (size_t)p * 32);
#pragma unroll
    for (int q = 0; q < 4; ++q) {
        uint4 v = xr[q];
        nv[q * 8 + 0] = bflo(v.x); nv[q * 8 + 1] = bfhi(v.x);
        nv[q * 8 + 2] = bflo(v.y); nv[q * 8 + 3] = bfhi(v.y);
        nv[q * 8 + 4] = bflo(v.z); nv[q * 8 + 5] = bfhi(v.z);
        nv[q * 8 + 6] = bflo(v.w); nv[q * 8 + 7] = bfhi(v.w);
    }
}

__global__ __launch_bounds__(256) void att_logits(
    const u16* __restrict__ net, const float* __restrict__ wi,
    const float* __restrict__ bi, float* __restrict__ lbuf,
    u32* __restrict__ mx, int M)
{
    int p = blockIdx.x * 256 + threadIdx.x;
    float l = -3.0e38f;
    if (p < M) {
        float nv[32];
        load_row32(net, p, nv);
        float s = bi[0];
#pragma unroll
        for (int c = 0; c < 32; ++c) s = fmaf(nv[c], wi[c], s);
        lbuf[p] = s;
        l = s;
    }
#pragma unroll
    for (int m = 1; m <= 32; m <<= 1) l = fmaxf(l, __shfl_xor(l, m, 64));
    if ((threadIdx.x & 63) == 0) {
        u32 b = __float_as_uint(l);
        u32 e = (b & 0x80000000u) ? ~b : (b | 0x80000000u);
        atomicMax(mx, e);
    }
}

__global__ __launch_bounds__(256) void att_accum(
    const u16* __restrict__ net, const float* __restrict__ lbuf,
    float* __restrict__ att, int M)
{
    int p = blockIdx.x * 256 + threadIdx.x;
    int lane = threadIdx.x & 63, wid = threadIdx.x >> 6;
    u32 um = __float_as_uint(att[0]);
    float mx = (um & 0x80000000u) ? __uint_as_float(um ^ 0x80000000u) : __uint_as_float(~um);
    float w = 0.f;
    float nv[32];
#pragma unroll
    for (int c = 0; c < 32; ++c) nv[c] = 0.f;
    if (p < M) {
        w = expf(lbuf[p] - mx);
        load_row32(net, p, nv);
    }
    float sel = 0.f;
#pragma unroll
    for (int c = 0; c < 32; ++c) {
        float s = w * nv[c];
#pragma unroll
        for (int m = 1; m <= 32; m <<= 1) s += __shfl_xor(s, m, 64);
        if (lane == c) sel = s;
    }
    {
        float s = w;
#pragma unroll
        for (int m = 1; m <= 32; m <<= 1) s += __shfl_xor(s, m, 64);
        if (lane == 32) sel = s;
    }
    __shared__ float red[4][33];
    if (lane < 33) red[wid][lane] = sel;
    __syncthreads();
    if (wid == 0 && lane < 33) {
        float t = red[0][lane] + red[1][lane] + red[2][lane] + red[3][lane];
        atomicAdd(lane < 32 ? &att[2 + lane] : &att[1], t);
    }
}

__global__ void att_ctx_k(const float* __restrict__ wk, const float* __restrict__ bk,
                          float* __restrict__ att)
{
    int o = threadIdx.x;
    if (o >= 32) return;
    float invS = 1.0f / att[1];
    float s = bk[o];
#pragma unroll
    for (int c = 0; c < 32; ++c) s = fmaf(att[2 + c] * invS, wk[c * 32 + o], s);
    att[34 + o] = s;
}

__global__ __launch_bounds__(256) void att_out_res(
    const u16* __restrict__ net, const u16* __restrict__ d,
    const float* __restrict__ wv, const float* __restrict__ bv,
    const float* __restrict__ wo, const float* __restrict__ bo,
    const float* __restrict__ att, u16* __restrict__ r, int M)
{
    int p = blockIdx.x * 256 + threadIdx.x;
    if (p >= M) return;
    float nv[32];
    load_row32(net, p, nv);
    float vv[32];
#pragma unroll
    for (int o = 0; o < 32; ++o) {
        float s = bv[o];
#pragma unroll
        for (int c = 0; c < 32; ++c) s = fmaf(nv[c], wv[c * 32 + o], s);
        vv[o] = s * att[34 + o];
    }
    float dv[32];
    load_row32(d, p, dv);
    u32 wd[16];
#pragma unroll
    for (int q = 0; q < 16; ++q) {
        float y[2];
#pragma unroll
        for (int t = 0; t < 2; ++t) {
            int oo = 2 * q + t;
            float s = bo[oo];
#pragma unroll
            for (int o = 0; o < 32; ++o) s = fmaf(vv[o], wo[o * 32 + oo], s);
            y[t] = fmaxf(s + dv[oo], 0.f);
        }
        wd[q] = pack2(y[0], y[1]);
    }
    uint4* dst = reinterpret_cast<uint4*>(r + (size_t)p * 32);
    uint4 v;
    v.x = wd[0];  v.y = wd[1];  v.z = wd[2];  v.w = wd[3];  dst[0] = v;
    v.x = wd[4];  v.y = wd[5];  v.z = wd[6];  v.w = wd[7];  dst[1] = v;
    v.x = wd[8];  v.y = wd[9];  v.z = wd[10]; v.w = wd[11]; dst[2] = v;
    v.x = wd[12]; v.y = wd[13]; v.z = wd[14]; v.w = wd[15]; dst[3] = v;
}

// ---------------- final: y = relu(bn(net2) + bn(ds)); out = y@Wcls + bcls ----------------
__global__ __launch_bounds__(256) void final_cls(
    const u16* __restrict__ net2, const u16* __restrict__ dsr,
    const float* __restrict__ st7, const float* __restrict__ st8,
    const float* __restrict__ gb7, const float* __restrict__ gb8,
    const float* __restrict__ wcls, const float* __restrict__ bcls,
    float* __restrict__ outp, float invM, int M)
{
    int p = blockIdx.x * 256 + threadIdx.x;
    if (p >= M) return;
    float nv[32], dv[32];
    load_row32(net2, p, nv);
    load_row32(dsr, p, dv);
    float y[32];
#pragma unroll
    for (int c = 0; c < 32; ++c) {
        float mu1 = st7[c] * invM;
        float var1 = fmaxf(st7[32 + c] * invM - mu1 * mu1, 0.f);
        float a1 = gb7[c] * rsqrtf(var1 + 1e-5f);
        float b1 = gb7[32 + c] - mu1 * a1;
        float mu2 = st8[c] * invM;
        float var2 = fmaxf(st8[32 + c] * invM - mu2 * mu2, 0.f);
        float a2 = gb8[c] * rsqrtf(var2 + 1e-5f);
        float b2 = gb8[32 + c] - mu2 * a2;
        float t = fmaf(a1, nv[c], b1) + fmaf(a2, dv[c], b2);
        y[c] = fmaxf(t, 0.f);
    }
#pragma unroll
    for (int j = 0; j < NCLSS; ++j) {
        float s = bcls[j];
#pragma unroll
        for (int c = 0; c < 32; ++c) s = fmaf(y[c], wcls[c * NCLSS + j], s);
        outp[(size_t)p * NCLSS + j] = s;
    }
}

// ---------------- host ----------------
extern "C" void kernel_launch(void* const* d_in, const int* in_sizes, int n_in,
                              void* d_out, int out_size, void* d_ws, size_t ws_size,
                              hipStream_t stream)
{
    char* wsb = (char*)d_ws;

    float* ST  = (float*)wsb;                 // 642 floats: 9*64 stats + 66 att
    float* ATT = ST + 576;
    float* L   = (float*)(wsb + 4096);        // N1 logits fp32
    u16* A = (u16*)(wsb + 65536);             // N*32 bf16 (7,680,000 B each)
    u16* B = (u16*)(wsb + 65536 + 7680000ull);
    u16* C = (u16*)(wsb + 65536 + 2 * 7680000ull);            // N1*32 (960,000 B)
    u16* D = (u16*)(wsb + 65536 + 2 * 7680000ull + 960000ull);
    u16* E = (u16*)(wsb + 65536 + 2 * 7680000ull + 2 * 960000ull);
    u16* F = (u16*)(wsb + 65536 + 2 * 7680000ull + 3 * 960000ull);          // cat N*64
    u16* G = (u16*)(wsb + 65536 + 2 * 7680000ull + 3 * 960000ull + 15360000ull); // net2 N*32

    // B-fragment weight buffers (padded to 4-s2 chunks: round KS2 up to x4)
    size_t wboff = 65536 + 2 * 7680000ull + 3 * 960000ull + 15360000ull + 7680000ull;
    auto wbsz = [](int KS2) { return (size_t)((KS2 + 3) / 4 * 4) * 2048; };
    uint4* wb_stem1 = (uint4*)(wsb + wboff);                 size_t o1 = wboff + wbsz(54);
    uint4* wb_down  = (uint4*)(wsb + o1);                    size_t o2 = o1 + wbsz(16);
    uint4* wb_res1  = (uint4*)(wsb + o2);                    size_t o3 = o2 + wbsz(54);
    uint4* wb_res2  = (uint4*)(wsb + o3);                    size_t o4 = o3 + wbsz(54);
    uint4* wb_up    = (uint4*)(wsb + o4);                    size_t o5 = o4 + wbsz(16);
    uint4* wb_fuse1 = (uint4*)(wsb + o5);                    size_t o6 = o5 + wbsz(108);
    uint4* wb_fuse2 = (uint4*)(wsb + o6);                    size_t o7 = o6 + wbsz(54);
    uint4* wb_ds    = (uint4*)(wsb + o7);                    size_t o8 = o7 + wbsz(4);

    // transposed nbr buffers (k-major)
    int* nbrT0 = (int*)(wsb + o8);                           size_t o9  = o8 + 27ull * NPTS * 4;
    int* nbrTd = (int*)(wsb + o9);                           size_t o10 = o9 + 8ull * N1PTS * 4;
    int* nbrT1 = (int*)(wsb + o10);                          size_t o11 = o10 + 27ull * N1PTS * 4;
    int* nbrTu = (int*)(wsb + o11);

    // inputs (fp32 per reference dtypes)
    const float* X        = (const float*)d_in[0];
    const float* Wstem0   = (const float*)d_in[1];
    const float* gb_stem0 = (const float*)d_in[2];
    const float* Wstem1   = (const float*)d_in[3];
    const float* gb_stem1 = (const float*)d_in[4];
    const float* Wdown    = (const float*)d_in[5];
    const float* gb_down  = (const float*)d_in[6];
    const float* Wres1    = (const float*)d_in[7];
    const float* gb_res1  = (const float*)d_in[8];
    const float* Wres2    = (const float*)d_in[9];
    const float* gb_res2  = (const float*)d_in[10];
    const float* wi = (const float*)d_in[11];
    const float* bi = (const float*)d_in[12];
    const float* wk = (const float*)d_in[13];
    const float* bk = (const float*)d_in[14];
    const float* wv = (const float*)d_in[15];
    const float* bv = (const float*)d_in[16];
    const float* wo = (const float*)d_in[17];
    const float* bo = (const float*)d_in[18];
    const float* Wup      = (const float*)d_in[19];
    const float* gb_up    = (const float*)d_in[20];
    const float* Wfuse1   = (const float*)d_in[21];
    const float* gb_fuse1 = (const float*)d_in[22];
    const float* Wfuse2   = (const float*)d_in[23];
    const float* gb_fuse2 = (const float*)d_in[24];
    const float* Wds      = (const float*)d_in[25];
    const float* gb_ds    = (const float*)d_in[26];
    const float* Wcls     = (const float*)d_in[27];
    const float* bcls     = (const float*)d_in[28];

    const int* nbr0     = (const int*)d_in[29];
    const int* nbr_down = (const int*)d_in[30];
    const int* nbr1     = (const int*)d_in[31];
    const int* nbr_up   = (const int*)d_in[32];

    const float invN  = 1.0f / (float)NPTS;
    const float invN1 = 1.0f / (float)N1PTS;

    hipMemsetAsync((void*)ST, 0, 642 * sizeof(float), stream);

    // transpose nbr arrays to k-major
    hipLaunchKernelGGL((transpose_nbr<27>), dim3(cdiv(NPTS, 256)), dim3(256), 0, stream,
                       nbr0, nbrT0, NPTS);
    hipLaunchKernelGGL((transpose_nbr<8>), dim3(cdiv(N1PTS, 256)), dim3(256), 0, stream,
                       nbr_down, nbrTd, N1PTS);
    hipLaunchKernelGGL((transpose_nbr<27>), dim3(cdiv(N1PTS, 256)), dim3(256), 0, stream,
                       nbr1, nbrT1, N1PTS);
    hipLaunchKernelGGL((transpose_nbr<8>), dim3(cdiv(NPTS, 256)), dim3(256), 0, stream,
                       nbr_up, nbrTu, NPTS);

    // pack all conv weights into MFMA B-fragment layout (hi/lo split)
    {
        WbArgs a;
        a.src[0] = Wstem1; a.dst[0] = wb_stem1; a.CPS[0] = 1; a.KS2[0] = 54;
        a.src[1] = Wdown;  a.dst[1] = wb_down;  a.CPS[1] = 1; a.KS2[1] = 16;
        a.src[2] = Wres1;  a.dst[2] = wb_res1;  a.CPS[2] = 1; a.KS2[2] = 54;
        a.src[3] = Wres2;  a.dst[3] = wb_res2;  a.CPS[3] = 1; a.KS2[3] = 54;
        a.src[4] = Wup;    a.dst[4] = wb_up;    a.CPS[4] = 1; a.KS2[4] = 16;
        a.src[5] = Wfuse1; a.dst[5] = wb_fuse1; a.CPS[5] = 2; a.KS2[5] = 108;
        a.src[6] = Wfuse2; a.dst[6] = wb_fuse2; a.CPS[6] = 1; a.KS2[6] = 54;
        a.src[7] = Wds;    a.dst[7] = wb_ds;    a.CPS[7] = 2; a.KS2[7] = 4;
        hipLaunchKernelGGL(convert_wb, dim3(108, 8), dim3(64), 0, stream, a);
    }

    const int gMN   = cdiv(NPTS, 64);            // 1875 (4 waves x 16 pts)
    const int gMN1  = cdiv(N1PTS, 64);           // 235
    const int gBN   = cdiv(NPTS * 4, 256);
    const int gBN1  = cdiv(N1PTS * 4, 256);
    const int gN1p  = cdiv(N1PTS, 256);
    const int gN    = cdiv(NPTS, 256);

    // stem
    hipLaunchKernelGGL(conv_x3, dim3(gMN), dim3(256), 0, stream,
                       X, nbrT0, Wstem0, A, ST + 0 * 64, NPTS);
    hipLaunchKernelGGL((bn_apply<true>), dim3(gBN), dim3(256), 0, stream,
                       A, ST + 0 * 64, gb_stem0, invN, NPTS * 4);
    hipLaunchKernelGGL((conv_mfma<27, 32, false>), dim3(gMN), dim3(256), 0, stream,
                       A, nbrT0, wb_stem1, B, ST + 1 * 64, NPTS);
    hipLaunchKernelGGL((bn_apply<true>), dim3(gBN), dim3(256), 0, stream,
                       B, ST + 1 * 64, gb_stem1, invN, NPTS * 4);   // B = x0

    // downsample
    hipLaunchKernelGGL((conv_mfma<8, 32, false>), dim3(gMN1), dim3(256), 0, stream,
                       B, nbrTd, wb_down, C, ST + 2 * 64, N1PTS);
    hipLaunchKernelGGL((bn_apply<true>), dim3(gBN1), dim3(256), 0, stream,
                       C, ST + 2 * 64, gb_down, invN1, N1PTS * 4);  // C = d

    // residual block convs
    hipLaunchKernelGGL((conv_mfma<27, 32, false>), dim3(gMN1), dim3(256), 0, stream,
                       C, nbrT1, wb_res1, D, ST + 3 * 64, N1PTS);
    hipLaunchKernelGGL((bn_apply<true>), dim3(gBN1), dim3(256), 0, stream,
                       D, ST + 3 * 64, gb_res1, invN1, N1PTS * 4);
    hipLaunchKernelGGL((conv_mfma<27, 32, false>), dim3(gMN1), dim3(256), 0, stream,
                       D, nbrT1, wb_res2, E, ST + 4 * 64, N1PTS);
    hipLaunchKernelGGL((bn_apply<false>), dim3(gBN1), dim3(256), 0, stream,
                       E, ST + 4 * 64, gb_res2, invN1, N1PTS * 4);  // E = net

    // attention + residual add (writes r into D)
    hipLaunchKernelGGL(att_logits, dim3(gN1p), dim3(256), 0, stream,
                       E, wi, bi, L, (u32*)ATT, N1PTS);
    hipLaunchKernelGGL(att_accum, dim3(gN1p), dim3(256), 0, stream, E, L, ATT, N1PTS);
    hipLaunchKernelGGL(att_ctx_k, dim3(1), dim3(64), 0, stream, wk, bk, ATT);
    hipLaunchKernelGGL(att_out_res, dim3(gN1p), dim3(256), 0, stream,
                       E, C, wv, bv, wo, bo, ATT, D, N1PTS);        // D = r

    // upsample + cat
    hipLaunchKernelGGL((conv_mfma<8, 32, false>), dim3(gMN), dim3(256), 0, stream,
                       D, nbrTu, wb_up, A, ST + 5 * 64, NPTS);
    hipLaunchKernelGGL(bnrelu_cat, dim3(gBN), dim3(256), 0, stream,
                       A, B, F, ST + 5 * 64, gb_up, invN, NPTS * 4); // F = cat

    // fuse residual block: ds first, then fuse1/fuse2
    hipLaunchKernelGGL((conv_mfma<1, 64, true>), dim3(gMN), dim3(256), 0, stream,
                       F, (const int*)nullptr, wb_ds, B, ST + 8 * 64, NPTS); // B = ds raw
    hipLaunchKernelGGL((conv_mfma<27, 64, false>), dim3(gMN), dim3(256), 0, stream,
                       F, nbrT0, wb_fuse1, A, ST + 6 * 64, NPTS);
    hipLaunchKernelGGL((bn_apply<true>), dim3(gBN), dim3(256), 0, stream,
                       A, ST + 6 * 64, gb_fuse1, invN, NPTS * 4);
    hipLaunchKernelGGL((conv_mfma<27, 32, false>), dim3(gMN), dim3(256), 0, stream,
                       A, nbrT0, wb_fuse2, G, ST + 7 * 64, NPTS);    // G = net2 raw

    // final fuse + classifier
    hipLaunchKernelGGL(final_cls, dim3(gN), dim3(256), 0, stream,
                       G, B, ST + 7 * 64, ST + 8 * 64, gb_fuse2, gb_ds,
                       Wcls, bcls, (float*)d_out, invN, NPTS);
}

// Round 8
// 542.893 us; speedup vs baseline: 13.9066x; 1.0582x over previous
//
#include <hip/hip_runtime.h>

typedef unsigned int u32;
typedef unsigned short u16;

#define NPTS 120000
#define N1PTS 15000
#define NCLSS 17

static inline int cdiv(int a, int b) { return (a + b - 1) / b; }

typedef __attribute__((ext_vector_type(8))) short bf16x8;
typedef __attribute__((ext_vector_type(4))) float f32x4;

// bf16 helpers (storage-only bf16; math fp32)
__device__ __forceinline__ float bflo(u32 u) { return __uint_as_float(u << 16); }
__device__ __forceinline__ float bfhi(u32 u) { return __uint_as_float(u & 0xFFFF0000u); }
__device__ __forceinline__ u32 f2bf(float f) {   // RNE
    u32 u = __float_as_uint(f);
    return (u + 0x7FFFu + ((u >> 16) & 1u)) >> 16;
}
__device__ __forceinline__ u32 pack2(float a, float b) { return f2bf(a) | (f2bf(b) << 16); }

// ---------------- nbr transpose: nbrT[k*M + p] = nbr[p*K + k] ----------------
template<int K>
__global__ __launch_bounds__(256) void transpose_nbr(
    const int* __restrict__ nbr, int* __restrict__ nbrT, int M)
{
    __shared__ int tile[256][K + 1];
    int p0 = blockIdx.x * 256;
    int t = threadIdx.x;
    int np = M - p0; if (np > 256) np = 256;
    int total = np * K;
    for (int i = t; i < total; i += 256) {
        int lp = i / K, k = i - lp * K;
        tile[lp][k] = nbr[(size_t)p0 * K + i];
    }
    __syncthreads();
    if (t < np) {
#pragma unroll
        for (int k = 0; k < K; ++k)
            nbrT[(size_t)k * M + p0 + t] = tile[t][k];
    }
}

// ---------------- weight -> B-fragment conversion (hi/lo bf16 split) ----------------
// uint4 index: s*256 + tile*128 + h*64 + lane  (s = k*CPS + c-chunk, tile = o-half, h=0 hi /1 lo)
struct WbArgs {
    const float* src[8];
    uint4* dst[8];
    int CPS[8];
    int KS2[8];    // K*CPS*2
};

__global__ __launch_bounds__(64) void convert_wb(WbArgs a) {
    int j = blockIdx.y;
    int s2 = blockIdx.x;
    if (s2 >= a.KS2[j]) return;
    int lane = threadIdx.x;
    int s = s2 >> 1, tile = s2 & 1;
    int CPS = a.CPS[j];
    int CIN = CPS * 32;
    int k = s / CPS, c0 = (s % CPS) * 32;
    int c = c0 + (lane >> 4) * 8;
    int o = tile * 16 + (lane & 15);
    const float* w = a.src[j] + ((size_t)k * CIN + c) * 32 + o;
    u32 hw[4], lw[4];
#pragma unroll
    for (int q = 0; q < 4; ++q) {
        float w0 = w[(2 * q) * 32], w1 = w[(2 * q + 1) * 32];
        u32 h0 = f2bf(w0), h1 = f2bf(w1);
        float r0 = w0 - __uint_as_float(h0 << 16);
        float r1 = w1 - __uint_as_float(h1 << 16);
        hw[q] = h0 | (h1 << 16);
        lw[q] = f2bf(r0) | (f2bf(r1) << 16);
    }
    uint4 hv; hv.x = hw[0]; hv.y = hw[1]; hv.z = hw[2]; hv.w = hw[3];
    uint4 lv; lv.x = lw[0]; lv.y = lw[1]; lv.z = lw[2]; lv.w = lw[3];
    a.dst[j][(size_t)(s2 * 2 + 0) * 64 + lane] = hv;
    a.dst[j][(size_t)(s2 * 2 + 1) * 64 + lane] = lv;
}

// ---------------- MFMA sparse conv, LDS-staged weights, deep prefetch pipeline ----------------
// Wave = 16 points x 32 outputs. Block's 4 waves share wb via LDS (double-buffered
// 2-step chunks, ONE raw s_barrier + lgkmcnt-only wait per chunk so gathers stay in
// flight across barriers - T4). Gathers issued 2 chunks ahead, nbr idx 3 chunks ahead.
template<int K, int CIN, bool IDENT>
__global__ __launch_bounds__(256, 6) void conv_mfma(
    const u16* __restrict__ src, const int* __restrict__ nbrT,
    const uint4* __restrict__ wb, u16* __restrict__ out,
    float* __restrict__ stats, int M)
{
    constexpr int CPS = CIN / 32;
    constexpr int KS = K * CPS;
    constexpr int NCH = (KS + 1) / 2;
    __shared__ uint4 wlds[2][512];   // 2 x (2 steps x 256 uint4) = 16 KB
    __shared__ float red[4][64];

    int tid = threadIdx.x;
    int lane = tid & 63, wid = tid >> 6;
    int p0 = blockIdx.x * 64 + wid * 16;
    int row = lane & 15, hi4 = lane >> 4;
    int p = p0 + row;
    bool rowok = p < M;
    const uint4 z4 = {0u, 0u, 0u, 0u};

    f32x4 acc0 = {0.f, 0.f, 0.f, 0.f};
    f32x4 acc1 = {0.f, 0.f, 0.f, 0.f};

    // idx for chunk cc (two steps). CPS==2: one k per chunk; CPS==1: two k's.
    auto loadIdx = [&](int cc, int& ia, int& ib) {
        ia = -1; ib = -1;
        int s0 = 2 * cc;
        if (rowok && s0 < KS) {
            int k0 = (CPS == 1) ? s0 : cc;
            ia = IDENT ? p : nbrT[(size_t)k0 * M + p];
            if (s0 + 1 < KS) {
                if (CPS == 2) ib = ia;
                else ib = IDENT ? p : nbrT[(size_t)(s0 + 1) * M + p];
            }
        }
    };
    auto issueGather = [&](int ia, int ib, uint4& g0, uint4& g1) {
        g0 = z4; g1 = z4;
        if (ia >= 0) g0 = reinterpret_cast<const uint4*>(src + (size_t)ia * CIN)[hi4];
        if (ib >= 0) g1 = reinterpret_cast<const uint4*>(src + (size_t)ib * CIN + (CPS == 2 ? 32 : 0))[hi4];
    };

    // prologue: idx chunks 0..2, gathers chunks 0..1, stage wb chunk 0
    int iA2, iB2, iA3, iB3;
    uint4 g0a, g0b, g1a, g1b;
    {
        int iA0, iB0, iA1, iB1;
        loadIdx(0, iA0, iB0);
        loadIdx(1, iA1, iB1);
        loadIdx(2, iA2, iB2);
        issueGather(iA0, iB0, g0a, g0b);
        issueGather(iA1, iB1, g1a, g1b);
    }
    wlds[0][tid] = wb[tid];
    wlds[0][256 + tid] = wb[256 + tid];

#pragma unroll 1
    for (int c = 0; c < NCH; ++c) {
        bool haveNext = (c + 1 < NCH);
        uint4 wr0 = z4, wr1 = z4;
        if (haveNext) {
            wr0 = wb[(size_t)(c + 1) * 512 + tid];
            wr1 = wb[(size_t)(c + 1) * 512 + 256 + tid];
        }
        uint4 f0 = z4, f1 = z4;
        if (c + 2 < NCH) issueGather(iA2, iB2, f0, f1);
        if (c + 3 < NCH) loadIdx(c + 3, iA3, iB3); else { iA3 = -1; iB3 = -1; }

        // wb-staging visibility only: drain LDS ops, raw barrier, keep vmem in flight
        asm volatile("s_waitcnt lgkmcnt(0)" ::: "memory");
        __builtin_amdgcn_s_barrier();
        asm volatile("" ::: "memory");

        const uint4* bl = wlds[c & 1];
        {
            bf16x8 a = __builtin_bit_cast(bf16x8, g0a);
            bf16x8 b0h = __builtin_bit_cast(bf16x8, bl[lane]);
            bf16x8 b0l = __builtin_bit_cast(bf16x8, bl[64 + lane]);
            bf16x8 b1h = __builtin_bit_cast(bf16x8, bl[128 + lane]);
            bf16x8 b1l = __builtin_bit_cast(bf16x8, bl[192 + lane]);
            acc0 = __builtin_amdgcn_mfma_f32_16x16x32_bf16(a, b0h, acc0, 0, 0, 0);
            acc0 = __builtin_amdgcn_mfma_f32_16x16x32_bf16(a, b0l, acc0, 0, 0, 0);
            acc1 = __builtin_amdgcn_mfma_f32_16x16x32_bf16(a, b1h, acc1, 0, 0, 0);
            acc1 = __builtin_amdgcn_mfma_f32_16x16x32_bf16(a, b1l, acc1, 0, 0, 0);
        }
        if (2 * c + 1 < KS) {
            bf16x8 a = __builtin_bit_cast(bf16x8, g0b);
            bf16x8 b0h = __builtin_bit_cast(bf16x8, bl[256 + lane]);
            bf16x8 b0l = __builtin_bit_cast(bf16x8, bl[320 + lane]);
            bf16x8 b1h = __builtin_bit_cast(bf16x8, bl[384 + lane]);
            bf16x8 b1l = __builtin_bit_cast(bf16x8, bl[448 + lane]);
            acc0 = __builtin_amdgcn_mfma_f32_16x16x32_bf16(a, b0h, acc0, 0, 0, 0);
            acc0 = __builtin_amdgcn_mfma_f32_16x16x32_bf16(a, b0l, acc0, 0, 0, 0);
            acc1 = __builtin_amdgcn_mfma_f32_16x16x32_bf16(a, b1h, acc1, 0, 0, 0);
            acc1 = __builtin_amdgcn_mfma_f32_16x16x32_bf16(a, b1l, acc1, 0, 0, 0);
        }
        if (haveNext) {
            wlds[(c + 1) & 1][tid] = wr0;
            wlds[(c + 1) & 1][256 + tid] = wr1;
        }
        g0a = g1a; g0b = g1b; g1a = f0; g1b = f1;
        iA2 = iA3; iB2 = iB3;
    }

    // store: lane holds D[point = hi4*4 + r][o = tile*16 + (lane&15)]
#pragma unroll
    for (int r = 0; r < 4; ++r) {
        int pp = p0 + hi4 * 4 + r;
        if (pp < M) {
            out[(size_t)pp * 32 + (lane & 15)] = (u16)f2bf(acc0[r]);
            out[(size_t)pp * 32 + 16 + (lane & 15)] = (u16)f2bf(acc1[r]);
        }
    }

    // bn stats
    float s0 = 0.f, q0 = 0.f, s1 = 0.f, q1 = 0.f;
#pragma unroll
    for (int r = 0; r < 4; ++r) {
        s0 += acc0[r]; q0 += acc0[r] * acc0[r];
        s1 += acc1[r]; q1 += acc1[r] * acc1[r];
    }
#pragma unroll
    for (int m = 16; m <= 32; m <<= 1) {
        s0 += __shfl_xor(s0, m, 64); q0 += __shfl_xor(q0, m, 64);
        s1 += __shfl_xor(s1, m, 64); q1 += __shfl_xor(q1, m, 64);
    }
    float val = (lane < 16) ? s0 : (lane < 32) ? s1 : (lane < 48) ? q0 : q1;
    red[wid][lane] = val;
    __syncthreads();
    if (wid == 0) {
        float t = red[0][lane] + red[1][lane] + red[2][lane] + red[3][lane];
        atomicAdd(&stats[lane], t);
    }
}

// ---------------- stem0 (CIN=3, fp32 x): scalar path, k split across 4 waves ----------------
__device__ __forceinline__ void reduce_store_stats(
    float (&acc)[32], int lane, int wid, bool act, int p,
    u16* __restrict__ out, float* __restrict__ stats)
{
    __shared__ float lds[3][64][17];
#pragma unroll
    for (int r = 0; r < 2; ++r) {
        if (wid > 0) {
#pragma unroll
            for (int j = 0; j < 16; ++j) lds[wid - 1][lane][j] = acc[r * 16 + j];
        }
        __syncthreads();
        if (wid == 0) {
#pragma unroll
            for (int w = 0; w < 3; ++w)
#pragma unroll
                for (int j = 0; j < 16; ++j) acc[r * 16 + j] += lds[w][lane][j];
        }
        __syncthreads();
    }
    if (wid == 0) {
        if (act) {
            u32 wd[16];
#pragma unroll
            for (int q = 0; q < 16; ++q) wd[q] = pack2(acc[2 * q], acc[2 * q + 1]);
            uint4* dst = reinterpret_cast<uint4*>(out + (size_t)p * 32);
            uint4 v;
            v.x = wd[0];  v.y = wd[1];  v.z = wd[2];  v.w = wd[3];  dst[0] = v;
            v.x = wd[4];  v.y = wd[5];  v.z = wd[6];  v.w = wd[7];  dst[1] = v;
            v.x = wd[8];  v.y = wd[9];  v.z = wd[10]; v.w = wd[11]; dst[2] = v;
            v.x = wd[12]; v.y = wd[13]; v.z = wd[14]; v.w = wd[15]; dst[3] = v;
        } else {
#pragma unroll
            for (int o = 0; o < 32; ++o) acc[o] = 0.f;
        }
        float sel1 = 0.f, sel2 = 0.f;
#pragma unroll
        for (int o = 0; o < 32; ++o) {
            float s1 = acc[o], s2 = acc[o] * acc[o];
#pragma unroll
            for (int m = 1; m <= 32; m <<= 1) { s1 += __shfl_xor(s1, m, 64); s2 += __shfl_xor(s2, m, 64); }
            if (lane == o) sel1 = s1;
            if (lane == o + 32) sel2 = s2;
        }
        atomicAdd(&stats[lane], lane < 32 ? sel1 : sel2);
    }
}

__global__ __launch_bounds__(256, 4) void conv_x3(
    const float* __restrict__ src, const int* __restrict__ nbrT,
    const float* __restrict__ W, u16* __restrict__ out,
    float* __restrict__ stats, int M)
{
    constexpr int K = 27;
    int lane = threadIdx.x & 63;
    int wid = __builtin_amdgcn_readfirstlane(threadIdx.x >> 6);
    int p = blockIdx.x * 64 + lane;
    bool act = p < M;
    constexpr int JMAX = 7;

    float acc[32];
#pragma unroll
    for (int o = 0; o < 32; ++o) acc[o] = 0.f;

    int idxs[JMAX];
#pragma unroll
    for (int j = 0; j < JMAX; ++j) {
        int k = wid + 4 * j;
        idxs[j] = (act && k < K) ? nbrT[(size_t)k * M + p] : -1;
    }
#pragma unroll
    for (int j = 0; j < JMAX; ++j) {
        int k = wid + 4 * j;
        if (k >= K) break;
        int idx = idxs[j];
        if (idx >= 0) {
            const float* __restrict__ xr = src + (size_t)idx * 3;
            const float* __restrict__ wk = W + (size_t)k * 3 * 32;
            float x0 = xr[0], x1 = xr[1], x2 = xr[2];
#pragma unroll
            for (int o = 0; o < 32; ++o) {
                float s = fmaf(x0, wk[o], 0.f);
                s = fmaf(x1, wk[32 + o], s);
                acc[o] += fmaf(x2, wk[64 + o], s);
            }
        }
    }
    reduce_store_stats(acc, lane, wid, act, p, out, stats);
}

// ---------------- bn apply in place on bf16 (thread = 8 channels) ----------------
template<bool RELU>
__global__ __launch_bounds__(256) void bn_apply(
    u16* __restrict__ buf, const float* __restrict__ stats,
    const float* __restrict__ gb, float invM, int total)
{
    int i = blockIdx.x * 256 + threadIdx.x;
    if (i >= total) return;
    int c0 = (i & 3) * 8;
    uint4 v = reinterpret_cast<uint4*>(buf)[i];
    u32 w[4] = { v.x, v.y, v.z, v.w };
    u32 r[4];
#pragma unroll
    for (int q = 0; q < 4; ++q) {
        int c = c0 + 2 * q;
        float mu0 = stats[c] * invM;
        float var0 = fmaxf(stats[32 + c] * invM - mu0 * mu0, 0.f);
        float a0 = gb[c] * rsqrtf(var0 + 1e-5f), b0 = gb[32 + c] - mu0 * a0;
        float mu1 = stats[c + 1] * invM;
        float var1 = fmaxf(stats[32 + c + 1] * invM - mu1 * mu1, 0.f);
        float a1 = gb[c + 1] * rsqrtf(var1 + 1e-5f), b1 = gb[32 + c + 1] - mu1 * a1;
        float y0 = fmaf(a0, bflo(w[q]), b0);
        float y1 = fmaf(a1, bfhi(w[q]), b1);
        if (RELU) { y0 = fmaxf(y0, 0.f); y1 = fmaxf(y1, 0.f); }
        r[q] = pack2(y0, y1);
    }
    uint4 o; o.x = r[0]; o.y = r[1]; o.z = r[2]; o.w = r[3];
    reinterpret_cast<uint4*>(buf)[i] = o;
}

// bn+relu(u raw) -> cat[:,0:32]; copy x0 -> cat[:,32:64]
__global__ __launch_bounds__(256) void bnrelu_cat(
    const u16* __restrict__ u, const u16* __restrict__ x0,
    u16* __restrict__ cat, const float* __restrict__ stats,
    const float* __restrict__ gb, float invM, int total)
{
    int i = blockIdx.x * 256 + threadIdx.x;
    if (i >= total) return;
    int p = i >> 2, j = i & 3;
    int c0 = j * 8;
    uint4 v = *reinterpret_cast<const uint4*>(u + (size_t)p * 32 + c0);
    u32 w[4] = { v.x, v.y, v.z, v.w };
    u32 r[4];
#pragma unroll
    for (int q = 0; q < 4; ++q) {
        int c = c0 + 2 * q;
        float mu0 = stats[c] * invM;
        float var0 = fmaxf(stats[32 + c] * invM - mu0 * mu0, 0.f);
        float a0 = gb[c] * rsqrtf(var0 + 1e-5f), b0 = gb[32 + c] - mu0 * a0;
        float mu1 = stats[c + 1] * invM;
        float var1 = fmaxf(stats[32 + c + 1] * invM - mu1 * mu1, 0.f);
        float a1 = gb[c + 1] * rsqrtf(var1 + 1e-5f), b1 = gb[32 + c + 1] - mu1 * a1;
        float y0 = fmaxf(fmaf(a0, bflo(w[q]), b0), 0.f);
        float y1 = fmaxf(fmaf(a1, bfhi(w[q]), b1), 0.f);
        r[q] = pack2(y0, y1);
    }
    uint4 o; o.x = r[0]; o.y = r[1]; o.z = r[2]; o.w = r[3];
    *reinterpret_cast<uint4*>(cat + (size_t)p * 64 + c0) = o;
    uint4 cp = *reinterpret_cast<const uint4*>(x0 + (size_t)p * 32 + c0);
    *reinterpret_cast<uint4*>(cat + (size_t)p * 64 + 32 + c0) = cp;
}

// ---------------- attention ----------------
__device__ __forceinline__ void load_row32(const u16* __restrict__ base, int p, float (&nv)[32])
{
    const uint4* xr = reinterpret_cast<const uint4*>(base + (size_t)p * 32);
#pragma unroll
    for (int q = 0; q < 4; ++q) {
        uint4 v = xr[q];
        nv[q * 8 + 0] = bflo(v.x); nv[q * 8 + 1] = bfhi(v.x);
        nv[q * 8 + 2] = bflo(v.y); nv[q * 8 + 3] = bfhi(v.y);
        nv[q * 8 + 4] = bflo(v.z); nv[q * 8 + 5] = bfhi(v.z);
        nv[q * 8 + 6] = bflo(v.w); nv[q * 8 + 7] = bfhi(v.w);
    }
}

__global__ __launch_bounds__(256) void att_logits(
    const u16* __restrict__ net, const float* __restrict__ wi,
    const float* __restrict__ bi, float* __restrict__ lbuf,
    u32* __restrict__ mx, int M)
{
    int p = blockIdx.x * 256 + threadIdx.x;
    float l = -3.0e38f;
    if (p < M) {
        float nv[32];
        load_row32(net, p, nv);
        float s = bi[0];
#pragma unroll
        for (int c = 0; c < 32; ++c) s = fmaf(nv[c], wi[c], s);
        lbuf[p] = s;
        l = s;
    }
#pragma unroll
    for (int m = 1; m <= 32; m <<= 1) l = fmaxf(l, __shfl_xor(l, m, 64));
    if ((threadIdx.x & 63) == 0) {
        u32 b = __float_as_uint(l);
        u32 e = (b & 0x80000000u) ? ~b : (b | 0x80000000u);
        atomicMax(mx, e);
    }
}

__global__ __launch_bounds__(256) void att_accum(
    const u16* __restrict__ net, const float* __restrict__ lbuf,
    float* __restrict__ att, int M)
{
    int p = blockIdx.x * 256 + threadIdx.x;
    int lane = threadIdx.x & 63, wid = threadIdx.x >> 6;
    u32 um = __float_as_uint(att[0]);
    float mx = (um & 0x80000000u) ? __uint_as_float(um ^ 0x80000000u) : __uint_as_float(~um);
    float w = 0.f;
    float nv[32];
#pragma unroll
    for (int c = 0; c < 32; ++c) nv[c] = 0.f;
    if (p < M) {
        w = expf(lbuf[p] - mx);
        load_row32(net, p, nv);
    }
    float sel = 0.f;
#pragma unroll
    for (int c = 0; c < 32; ++c) {
        float s = w * nv[c];
#pragma unroll
        for (int m = 1; m <= 32; m <<= 1) s += __shfl_xor(s, m, 64);
        if (lane == c) sel = s;
    }
    {
        float s = w;
#pragma unroll
        for (int m = 1; m <= 32; m <<= 1) s += __shfl_xor(s, m, 64);
        if (lane == 32) sel = s;
    }
    __shared__ float red[4][33];
    if (lane < 33) red[wid][lane] = sel;
    __syncthreads();
    if (wid == 0 && lane < 33) {
        float t = red[0][lane] + red[1][lane] + red[2][lane] + red[3][lane];
        atomicAdd(lane < 32 ? &att[2 + lane] : &att[1], t);
    }
}

__global__ void att_ctx_k(const float* __restrict__ wk, const float* __restrict__ bk,
                          float* __restrict__ att)
{
    int o = threadIdx.x;
    if (o >= 32) return;
    float invS = 1.0f / att[1];
    float s = bk[o];
#pragma unroll
    for (int c = 0; c < 32; ++c) s = fmaf(att[2 + c] * invS, wk[c * 32 + o], s);
    att[34 + o] = s;
}

__global__ __launch_bounds__(256) void att_out_res(
    const u16* __restrict__ net, const u16* __restrict__ d,
    const float* __restrict__ wv, const float* __restrict__ bv,
    const float* __restrict__ wo, const float* __restrict__ bo,
    const float* __restrict__ att, u16* __restrict__ r, int M)
{
    int p = blockIdx.x * 256 + threadIdx.x;
    if (p >= M) return;
    float nv[32];
    load_row32(net, p, nv);
    float vv[32];
#pragma unroll
    for (int o = 0; o < 32; ++o) {
        float s = bv[o];
#pragma unroll
        for (int c = 0; c < 32; ++c) s = fmaf(nv[c], wv[c * 32 + o], s);
        vv[o] = s * att[34 + o];
    }
    float dv[32];
    load_row32(d, p, dv);
    u32 wd[16];
#pragma unroll
    for (int q = 0; q < 16; ++q) {
        float y[2];
#pragma unroll
        for (int t = 0; t < 2; ++t) {
            int oo = 2 * q + t;
            float s = bo[oo];
#pragma unroll
            for (int o = 0; o < 32; ++o) s = fmaf(vv[o], wo[o * 32 + oo], s);
            y[t] = fmaxf(s + dv[oo], 0.f);
        }
        wd[q] = pack2(y[0], y[1]);
    }
    uint4* dst = reinterpret_cast<uint4*>(r + (size_t)p * 32);
    uint4 v;
    v.x = wd[0];  v.y = wd[1];  v.z = wd[2];  v.w = wd[3];  dst[0] = v;
    v.x = wd[4];  v.y = wd[5];  v.z = wd[6];  v.w = wd[7];  dst[1] = v;
    v.x = wd[8];  v.y = wd[9];  v.z = wd[10]; v.w = wd[11]; dst[2] = v;
    v.x = wd[12]; v.y = wd[13]; v.z = wd[14]; v.w = wd[15]; dst[3] = v;
}

// ---------------- final: y = relu(bn(net2) + bn(ds)); out = y@Wcls + bcls ----------------
__global__ __launch_bounds__(256) void final_cls(
    const u16* __restrict__ net2, const u16* __restrict__ dsr,
    const float* __restrict__ st7, const float* __restrict__ st8,
    const float* __restrict__ gb7, const float* __restrict__ gb8,
    const float* __restrict__ wcls, const float* __restrict__ bcls,
    float* __restrict__ outp, float invM, int M)
{
    int p = blockIdx.x * 256 + threadIdx.x;
    if (p >= M) return;
    float nv[32], dv[32];
    load_row32(net2, p, nv);
    load_row32(dsr, p, dv);
    float y[32];
#pragma unroll
    for (int c = 0; c < 32; ++c) {
        float mu1 = st7[c] * invM;
        float var1 = fmaxf(st7[32 + c] * invM - mu1 * mu1, 0.f);
        float a1 = gb7[c] * rsqrtf(var1 + 1e-5f);
        float b1 = gb7[32 + c] - mu1 * a1;
        float mu2 = st8[c] * invM;
        float var2 = fmaxf(st8[32 + c] * invM - mu2 * mu2, 0.f);
        float a2 = gb8[c] * rsqrtf(var2 + 1e-5f);
        float b2 = gb8[32 + c] - mu2 * a2;
        float t = fmaf(a1, nv[c], b1) + fmaf(a2, dv[c], b2);
        y[c] = fmaxf(t, 0.f);
    }
#pragma unroll
    for (int j = 0; j < NCLSS; ++j) {
        float s = bcls[j];
#pragma unroll
        for (int c = 0; c < 32; ++c) s = fmaf(y[c], wcls[c * NCLSS + j], s);
        outp[(size_t)p * NCLSS + j] = s;
    }
}

// ---------------- host ----------------
extern "C" void kernel_launch(void* const* d_in, const int* in_sizes, int n_in,
                              void* d_out, int out_size, void* d_ws, size_t ws_size,
                              hipStream_t stream)
{
    char* wsb = (char*)d_ws;

    float* ST  = (float*)wsb;                 // 642 floats: 9*64 stats + 66 att
    float* ATT = ST + 576;
    float* L   = (float*)(wsb + 4096);        // N1 logits fp32
    u16* A = (u16*)(wsb + 65536);             // N*32 bf16 (7,680,000 B each)
    u16* B = (u16*)(wsb + 65536 + 7680000ull);
    u16* C = (u16*)(wsb + 65536 + 2 * 7680000ull);            // N1*32 (960,000 B)
    u16* D = (u16*)(wsb + 65536 + 2 * 7680000ull + 960000ull);
    u16* E = (u16*)(wsb + 65536 + 2 * 7680000ull + 2 * 960000ull);
    u16* F = (u16*)(wsb + 65536 + 2 * 7680000ull + 3 * 960000ull);          // cat N*64
    u16* G = (u16*)(wsb + 65536 + 2 * 7680000ull + 3 * 960000ull + 15360000ull); // net2 N*32

    // B-fragment weight buffers (padded to 4-s2 chunks: round KS2 up to x4)
    size_t wboff = 65536 + 2 * 7680000ull + 3 * 960000ull + 15360000ull + 7680000ull;
    auto wbsz = [](int KS2) { return (size_t)((KS2 + 3) / 4 * 4) * 2048; };
    uint4* wb_stem1 = (uint4*)(wsb + wboff);                 size_t o1 = wboff + wbsz(54);
    uint4* wb_down  = (uint4*)(wsb + o1);                    size_t o2 = o1 + wbsz(16);
    uint4* wb_res1  = (uint4*)(wsb + o2);                    size_t o3 = o2 + wbsz(54);
    uint4* wb_res2  = (uint4*)(wsb + o3);                    size_t o4 = o3 + wbsz(54);
    uint4* wb_up    = (uint4*)(wsb + o4);                    size_t o5 = o4 + wbsz(16);
    uint4* wb_fuse1 = (uint4*)(wsb + o5);                    size_t o6 = o5 + wbsz(108);
    uint4* wb_fuse2 = (uint4*)(wsb + o6);                    size_t o7 = o6 + wbsz(54);
    uint4* wb_ds    = (uint4*)(wsb + o7);                    size_t o8 = o7 + wbsz(4);

    // transposed nbr buffers (k-major)
    int* nbrT0 = (int*)(wsb + o8);                           size_t o9  = o8 + 27ull * NPTS * 4;
    int* nbrTd = (int*)(wsb + o9);                           size_t o10 = o9 + 8ull * N1PTS * 4;
    int* nbrT1 = (int*)(wsb + o10);                          size_t o11 = o10 + 27ull * N1PTS * 4;
    int* nbrTu = (int*)(wsb + o11);

    // inputs (fp32 per reference dtypes)
    const float* X        = (const float*)d_in[0];
    const float* Wstem0   = (const float*)d_in[1];
    const float* gb_stem0 = (const float*)d_in[2];
    const float* Wstem1   = (const float*)d_in[3];
    const float* gb_stem1 = (const float*)d_in[4];
    const float* Wdown    = (const float*)d_in[5];
    const float* gb_down  = (const float*)d_in[6];
    const float* Wres1    = (const float*)d_in[7];
    const float* gb_res1  = (const float*)d_in[8];
    const float* Wres2    = (const float*)d_in[9];
    const float* gb_res2  = (const float*)d_in[10];
    const float* wi = (const float*)d_in[11];
    const float* bi = (const float*)d_in[12];
    const float* wk = (const float*)d_in[13];
    const float* bk = (const float*)d_in[14];
    const float* wv = (const float*)d_in[15];
    const float* bv = (const float*)d_in[16];
    const float* wo = (const float*)d_in[17];
    const float* bo = (const float*)d_in[18];
    const float* Wup      = (const float*)d_in[19];
    const float* gb_up    = (const float*)d_in[20];
    const float* Wfuse1   = (const float*)d_in[21];
    const float* gb_fuse1 = (const float*)d_in[22];
    const float* Wfuse2   = (const float*)d_in[23];
    const float* gb_fuse2 = (const float*)d_in[24];
    const float* Wds      = (const float*)d_in[25];
    const float* gb_ds    = (const float*)d_in[26];
    const float* Wcls     = (const float*)d_in[27];
    const float* bcls     = (const float*)d_in[28];

    const int* nbr0     = (const int*)d_in[29];
    const int* nbr_down = (const int*)d_in[30];
    const int* nbr1     = (const int*)d_in[31];
    const int* nbr_up   = (const int*)d_in[32];

    const float invN  = 1.0f / (float)NPTS;
    const float invN1 = 1.0f / (float)N1PTS;

    hipMemsetAsync((void*)ST, 0, 642 * sizeof(float), stream);

    // transpose nbr arrays to k-major
    hipLaunchKernelGGL((transpose_nbr<27>), dim3(cdiv(NPTS, 256)), dim3(256), 0, stream,
                       nbr0, nbrT0, NPTS);
    hipLaunchKernelGGL((transpose_nbr<8>), dim3(cdiv(N1PTS, 256)), dim3(256), 0, stream,
                       nbr_down, nbrTd, N1PTS);
    hipLaunchKernelGGL((transpose_nbr<27>), dim3(cdiv(N1PTS, 256)), dim3(256), 0, stream,
                       nbr1, nbrT1, N1PTS);
    hipLaunchKernelGGL((transpose_nbr<8>), dim3(cdiv(NPTS, 256)), dim3(256), 0, stream,
                       nbr_up, nbrTu, NPTS);

    // pack all conv weights into MFMA B-fragment layout (hi/lo split)
    {
        WbArgs a;
        a.src[0] = Wstem1; a.dst[0] = wb_stem1; a.CPS[0] = 1; a.KS2[0] = 54;
        a.src[1] = Wdown;  a.dst[1] = wb_down;  a.CPS[1] = 1; a.KS2[1] = 16;
        a.src[2] = Wres1;  a.dst[2] = wb_res1;  a.CPS[2] = 1; a.KS2[2] = 54;
        a.src[3] = Wres2;  a.dst[3] = wb_res2;  a.CPS[3] = 1; a.KS2[3] = 54;
        a.src[4] = Wup;    a.dst[4] = wb_up;    a.CPS[4] = 1; a.KS2[4] = 16;
        a.src[5] = Wfuse1; a.dst[5] = wb_fuse1; a.CPS[5] = 2; a.KS2[5] = 108;
        a.src[6] = Wfuse2; a.dst[6] = wb_fuse2; a.CPS[6] = 1; a.KS2[6] = 54;
        a.src[7] = Wds;    a.dst[7] = wb_ds;    a.CPS[7] = 2; a.KS2[7] = 4;
        hipLaunchKernelGGL(convert_wb, dim3(108, 8), dim3(64), 0, stream, a);
    }

    const int gMN   = cdiv(NPTS, 64);            // 1875 (4 waves x 16 pts)
    const int gMN1  = cdiv(N1PTS, 64);           // 235
    const int gBN   = cdiv(NPTS * 4, 256);
    const int gBN1  = cdiv(N1PTS * 4, 256);
    const int gN1p  = cdiv(N1PTS, 256);
    const int gN    = cdiv(NPTS, 256);

    // stem
    hipLaunchKernelGGL(conv_x3, dim3(gMN), dim3(256), 0, stream,
                       X, nbrT0, Wstem0, A, ST + 0 * 64, NPTS);
    hipLaunchKernelGGL((bn_apply<true>), dim3(gBN), dim3(256), 0, stream,
                       A, ST + 0 * 64, gb_stem0, invN, NPTS * 4);
    hipLaunchKernelGGL((conv_mfma<27, 32, false>), dim3(gMN), dim3(256), 0, stream,
                       A, nbrT0, wb_stem1, B, ST + 1 * 64, NPTS);
    hipLaunchKernelGGL((bn_apply<true>), dim3(gBN), dim3(256), 0, stream,
                       B, ST + 1 * 64, gb_stem1, invN, NPTS * 4);   // B = x0

    // downsample
    hipLaunchKernelGGL((conv_mfma<8, 32, false>), dim3(gMN1), dim3(256), 0, stream,
                       B, nbrTd, wb_down, C, ST + 2 * 64, N1PTS);
    hipLaunchKernelGGL((bn_apply<true>), dim3(gBN1), dim3(256), 0, stream,
                       C, ST + 2 * 64, gb_down, invN1, N1PTS * 4);  // C = d

    // residual block convs
    hipLaunchKernelGGL((conv_mfma<27, 32, false>), dim3(gMN1), dim3(256), 0, stream,
                       C, nbrT1, wb_res1, D, ST + 3 * 64, N1PTS);
    hipLaunchKernelGGL((bn_apply<true>), dim3(gBN1), dim3(256), 0, stream,
                       D, ST + 3 * 64, gb_res1, invN1, N1PTS * 4);
    hipLaunchKernelGGL((conv_mfma<27, 32, false>), dim3(gMN1), dim3(256), 0, stream,
                       D, nbrT1, wb_res2, E, ST + 4 * 64, N1PTS);
    hipLaunchKernelGGL((bn_apply<false>), dim3(gBN1), dim3(256), 0, stream,
                       E, ST + 4 * 64, gb_res2, invN1, N1PTS * 4);  // E = net

    // attention + residual add (writes r into D)
    hipLaunchKernelGGL(att_logits, dim3(gN1p), dim3(256), 0, stream,
                       E, wi, bi, L, (u32*)ATT, N1PTS);
    hipLaunchKernelGGL(att_accum, dim3(gN1p), dim3(256), 0, stream, E, L, ATT, N1PTS);
    hipLaunchKernelGGL(att_ctx_k, dim3(1), dim3(64), 0, stream, wk, bk, ATT);
    hipLaunchKernelGGL(att_out_res, dim3(gN1p), dim3(256), 0, stream,
                       E, C, wv, bv, wo, bo, ATT, D, N1PTS);        // D = r

    // upsample + cat
    hipLaunchKernelGGL((conv_mfma<8, 32, false>), dim3(gMN), dim3(256), 0, stream,
                       D, nbrTu, wb_up, A, ST + 5 * 64, NPTS);
    hipLaunchKernelGGL(bnrelu_cat, dim3(gBN), dim3(256), 0, stream,
                       A, B, F, ST + 5 * 64, gb_up, invN, NPTS * 4); // F = cat

    // fuse residual block: ds first, then fuse1/fuse2
    hipLaunchKernelGGL((conv_mfma<1, 64, true>), dim3(gMN), dim3(256), 0, stream,
                       F, (const int*)nullptr, wb_ds, B, ST + 8 * 64, NPTS); // B = ds raw
    hipLaunchKernelGGL((conv_mfma<27, 64, false>), dim3(gMN), dim3(256), 0, stream,
                       F, nbrT0, wb_fuse1, A, ST + 6 * 64, NPTS);
    hipLaunchKernelGGL((bn_apply<true>), dim3(gBN), dim3(256), 0, stream,
                       A, ST + 6 * 64, gb_fuse1, invN, NPTS * 4);
    hipLaunchKernelGGL((conv_mfma<27, 32, false>), dim3(gMN), dim3(256), 0, stream,
                       A, nbrT0, wb_fuse2, G, ST + 7 * 64, NPTS);    // G = net2 raw

    // final fuse + classifier
    hipLaunchKernelGGL(final_cls, dim3(gN), dim3(256), 0, stream,
                       G, B, ST + 7 * 64, ST + 8 * 64, gb_fuse2, gb_ds,
                       Wcls, bcls, (float*)d_out, invN, NPTS);
}